// Round 1
// baseline (4171.903 us; speedup 1.0000x reference)
//
#include <hip/hip_runtime.h>

#define N_NODE 50000
#define N_PRICE 100
#define N_CB 50
#define N_CM 500
#define EMB 128
#define NNZE 1000000
#define NCH 24
#define CS 2112        /* 33 tiles of 64 cols; 24*2112 = 50688 >= 50000 */
#define RSTRIDE 132    /* 128 num + den + Z + pad */
#define IB 64
#define KT 64
#define RB 32
#define KT2 64

// ---- monotone float<->uint keys for atomic min/max on floats ----
__device__ inline unsigned fkey(float f){
    unsigned b = __float_as_uint(f);
    return (b & 0x80000000u) ? ~b : (b | 0x80000000u);
}
__device__ inline float fdekey(unsigned k){
    unsigned b = (k & 0x80000000u) ? (k & 0x7fffffffu) : ~k;
    return __uint_as_float(b);
}

// ---------------------------------------------------------------------------
// rowsum: s[row] = sum over 128 dims, for all 4 node types. Also (idempotently)
// initializes the min/max slots so the next kernel's atomics have a base.
// one wave per row.
__global__ __launch_bounds__(256) void k_rowsum(
    const float* __restrict__ e_v, const float* __restrict__ e_p,
    const float* __restrict__ e_cb, const float* __restrict__ e_cm,
    float* __restrict__ s_all, unsigned* __restrict__ mm)
{
    if (blockIdx.x == 0 && threadIdx.x < 8)
        mm[threadIdx.x] = (threadIdx.x & 1) ? 0u : 0xFFFFFFFFu;
    int wid  = (blockIdx.x * 256 + threadIdx.x) >> 6;
    int lane = threadIdx.x & 63;
    const int NT = N_NODE + N_PRICE + N_CB + N_CM;
    if (wid >= NT) return;
    const float* src; int lr;
    if (wid < N_NODE)                { src = e_v;  lr = wid; }
    else if (wid < N_NODE+N_PRICE)   { src = e_p;  lr = wid - N_NODE; }
    else if (wid < N_NODE+N_PRICE+N_CB){ src = e_cb; lr = wid - N_NODE - N_PRICE; }
    else                             { src = e_cm; lr = wid - N_NODE - N_PRICE - N_CB; }
    float2 v = ((const float2*)(src + (size_t)lr * EMB))[lane];
    float sum = v.x + v.y;
    #pragma unroll
    for (int o = 32; o > 0; o >>= 1) sum += __shfl_down(sum, o, 64);
    if (lane == 0) s_all[wid] = sum;
}

// min/max of s per type (block pre-reduce in LDS, then global atomics)
__global__ __launch_bounds__(256) void k_minmax(
    const float* __restrict__ s_all, unsigned* __restrict__ mm)
{
    __shared__ unsigned smin[4], smax[4];
    int t = threadIdx.x;
    if (t < 4){ smin[t] = 0xFFFFFFFFu; smax[t] = 0u; }
    __syncthreads();
    int gid = blockIdx.x * 256 + t;
    const int NT = N_NODE + N_PRICE + N_CB + N_CM;
    if (gid < NT){
        int ty = (gid < N_NODE) ? 0 :
                 (gid < N_NODE+N_PRICE) ? 1 :
                 (gid < N_NODE+N_PRICE+N_CB) ? 2 : 3;
        unsigned k = fkey(s_all[gid]);
        atomicMin(&smin[ty], k);
        atomicMax(&smax[ty], k);
    }
    __syncthreads();
    if (t < 4){
        if (smin[t] != 0xFFFFFFFFu) atomicMin(&mm[2*t],   smin[t]);
        if (smax[t] != 0u)          atomicMax(&mm[2*t+1], smax[t]);
    }
}

// ---------------------------------------------------------------------------
// V-side intra gate: out[i,:] = sum_j w_ij emb2[j,:] / (den_i + 1e-8 Z_i)
// for i in [0,50000), j in [0,K), K in {100,50,500}. Tiled LDS GEMM with the
// weight tile generated on the fly.
// block = 256 threads, IB=64 rows/block. LDS ~51KB -> 3 blocks/CU.
__global__ __launch_bounds__(256) void k_intra_v(
    const float* __restrict__ adj, const float* __restrict__ matv,
    const float* __restrict__ emb2, const float* __restrict__ s_src,
    const unsigned* __restrict__ mm2, float* __restrict__ out, int K)
{
    __shared__ float sh_s[512];
    __shared__ float sh_c[IB], sh_M[IB], sh_inv[IB];
    __shared__ float sh_w[IB][KT + 1];
    __shared__ float sh_e[KT][EMB];
    int tid = threadIdx.x;
    int i0  = blockIdx.x * IB;

    for (int j = tid; j < K; j += 256) sh_s[j] = s_src[j];
    if (tid < IB){
        int i = i0 + tid;
        float c = (i < N_NODE) ? matv[i] : 0.f;
        float smin = fdekey(mm2[0]), smax = fdekey(mm2[1]);
        sh_c[tid] = c;
        sh_M[tid] = (c >= 0.f) ? c * smax : c * smin;
    }
    __syncthreads();

    float Z = 0.f, den = 0.f;
    if (tid < IB){
        float c = sh_c[tid], M = sh_M[tid];
        for (int j = 0; j < K; j++) Z += __expf(c * sh_s[j] - M);
    }

    float acc[4][8];
    #pragma unroll
    for (int r = 0; r < 4; r++)
        #pragma unroll
        for (int d = 0; d < 8; d++) acc[r][d] = 0.f;
    int dg = tid & 15, rg = tid >> 4;

    int ntile = (K + KT - 1) / KT;
    for (int t = 0; t < ntile; t++){
        int k0 = t * KT;
        __syncthreads();
        // stage E tile (zero-fill OOB so 0*garbage never produces NaN)
        #pragma unroll
        for (int q = 0; q < 8; q++){
            int f  = tid + q * 256;
            int jl = f >> 5;
            int d  = (f & 31) * 4;
            int j  = k0 + jl;
            float4 v = (j < K) ? ((const float4*)(emb2 + (size_t)j * EMB + d))[0]
                               : make_float4(0.f,0.f,0.f,0.f);
            ((float4*)&sh_e[jl][d])[0] = v;
        }
        // build W tile
        #pragma unroll
        for (int p = 0; p < 16; p++){
            int idx = tid + p * 256;
            int rl = idx >> 6, jl = idx & 63;
            int i = i0 + rl, j = k0 + jl;
            float w = 0.f;
            if (j < K && i < N_NODE){
                float e = __expf(sh_c[rl] * sh_s[j] - sh_M[rl]);
                w = e * adj[(size_t)i * K + j];
            }
            sh_w[rl][jl] = w;
        }
        __syncthreads();
        if (tid < IB){
            float d0 = 0.f;
            #pragma unroll 8
            for (int jl = 0; jl < KT; jl++) d0 += sh_w[tid][jl];
            den += d0;
        }
        #pragma unroll 4
        for (int jl = 0; jl < KT; jl++){
            float4 e0 = ((const float4*)&sh_e[jl][dg*8])[0];
            float4 e1 = ((const float4*)&sh_e[jl][dg*8+4])[0];
            #pragma unroll
            for (int r = 0; r < 4; r++){
                float w = sh_w[rg*4 + r][jl];
                acc[r][0] += w*e0.x; acc[r][1] += w*e0.y;
                acc[r][2] += w*e0.z; acc[r][3] += w*e0.w;
                acc[r][4] += w*e1.x; acc[r][5] += w*e1.y;
                acc[r][6] += w*e1.z; acc[r][7] += w*e1.w;
            }
        }
    }
    __syncthreads();
    if (tid < IB) sh_inv[tid] = 1.f / (den + 1e-8f * Z);
    __syncthreads();
    #pragma unroll
    for (int r = 0; r < 4; r++){
        int i = i0 + rg*4 + r;
        if (i < N_NODE){
            float inv = sh_inv[rg*4 + r];
            ((float4*)(out + (size_t)i*EMB + dg*8))[0] =
                make_float4(acc[r][0]*inv, acc[r][1]*inv, acc[r][2]*inv, acc[r][3]*inv);
            ((float4*)(out + (size_t)i*EMB + dg*8 + 4))[0] =
                make_float4(acc[r][4]*inv, acc[r][5]*inv, acc[r][6]*inv, acc[r][7]*inv);
        }
    }
}

// ---------------------------------------------------------------------------
// inter gate for items: one wave per row; 4 shuffle-reduced dots with W.
__global__ __launch_bounds__(256) void k_inter_item(
    const float* __restrict__ e0, const float* __restrict__ g1,
    const float* __restrict__ g2, const float* __restrict__ g3,
    const float* __restrict__ W, const float* __restrict__ b,
    float* __restrict__ out)
{
    int wid  = (blockIdx.x * 256 + threadIdx.x) >> 6;
    int lane = threadIdx.x & 63;
    if (wid >= N_NODE) return;
    size_t base = (size_t)wid * EMB + lane * 2;
    float2 v0 = *(const float2*)(e0 + base);
    float2 v1 = *(const float2*)(g1 + base);
    float2 v2 = *(const float2*)(g2 + base);
    float2 v3 = *(const float2*)(g3 + base);
    float2 w2 = *(const float2*)(W + lane * 2);
    float d0 = v0.x*w2.x + v0.y*w2.y;
    float d1 = v1.x*w2.x + v1.y*w2.y;
    float d2 = v2.x*w2.x + v2.y*w2.y;
    float d3 = v3.x*w2.x + v3.y*w2.y;
    #pragma unroll
    for (int o = 32; o > 0; o >>= 1){
        d0 += __shfl_xor(d0, o, 64); d1 += __shfl_xor(d1, o, 64);
        d2 += __shfl_xor(d2, o, 64); d3 += __shfl_xor(d3, o, 64);
    }
    float bb = b[0];
    float s0 = __expf(d0 + bb), s1 = __expf(d1 + bb);
    float s2 = __expf(d2 + bb), s3 = __expf(d3 + bb);
    float inv = 1.f / (s0 + s1 + s2 + s3);
    float2 o2;
    o2.x = (s0*v0.x + s1*v1.x + s2*v2.x + s3*v3.x) * inv;
    o2.y = (s0*v0.y + s1*v1.y + s2*v2.y + s3*v3.y) * inv;
    *(float2*)(out + base) = o2;
}

// sparse COO spmm: out[row] += val * emb[col]; one wave per nnz, atomics.
__global__ __launch_bounds__(256) void k_spmm(
    const int* __restrict__ rows_, const int* __restrict__ cols_,
    const float* __restrict__ vals, const float* __restrict__ emb,
    float* __restrict__ out)
{
    int n    = (blockIdx.x * 256 + threadIdx.x) >> 6;
    int lane = threadIdx.x & 63;
    if (n >= NNZE) return;
    int r = rows_[n], c = cols_[n];
    float v = vals[n];
    float2 e = *(const float2*)(emb + (size_t)c * EMB + lane * 2);
    atomicAdd(out + (size_t)r * EMB + lane * 2,     v * e.x);
    atomicAdd(out + (size_t)r * EMB + lane * 2 + 1, v * e.y);
}

// ---------------------------------------------------------------------------
// transposed-side intra gate, phase 1: partial (num[128], den, Z) per
// (row, chunk). RB=32 rows/block, chunk = CS cols staged in KT2-col tiles.
__global__ __launch_bounds__(256) void k_intra_tv_partial(
    const float* __restrict__ adj,   // [rows][N_NODE]
    const float* __restrict__ matv,  // [rows]
    const float* __restrict__ emb,   // [N_NODE][EMB]
    const float* __restrict__ s_v,   // [N_NODE]
    const unsigned* __restrict__ mm2,
    float* __restrict__ part, int baseR, int rows)
{
    __shared__ float sh_c[RB], sh_M[RB];
    __shared__ float sh_sv[KT2];
    __shared__ float sh_w[RB][KT2 + 1];
    __shared__ float sh_e[KT2][EMB];
    __shared__ float shZ[RB], shD[RB];
    int tid = threadIdx.x;
    int rb = blockIdx.x / NCH;
    int ch = blockIdx.x % NCH;
    int r0 = rb * RB;
    if (tid < RB){
        int r = r0 + tid;
        float c = (r < rows) ? matv[r] : 0.f;
        float smin = fdekey(mm2[0]), smax = fdekey(mm2[1]);
        sh_c[tid] = c;
        sh_M[tid] = (c >= 0.f) ? c * smax : c * smin;
        shZ[tid] = 0.f; shD[tid] = 0.f;
    }
    float zacc[8], dacc[8];
    #pragma unroll
    for (int p = 0; p < 8; p++){ zacc[p] = 0.f; dacc[p] = 0.f; }
    float acc[2][8];
    #pragma unroll
    for (int r = 0; r < 2; r++)
        #pragma unroll
        for (int d = 0; d < 8; d++) acc[r][d] = 0.f;
    int dg = tid & 15, rg = tid >> 4;
    int j0 = ch * CS;
    __syncthreads();

    for (int t = 0; t < CS / KT2; t++){
        int k0 = j0 + t * KT2;
        __syncthreads();
        if (tid < KT2) sh_sv[tid] = (k0 + tid < N_NODE) ? s_v[k0 + tid] : 0.f;
        #pragma unroll
        for (int q = 0; q < 8; q++){
            int f = tid + q * 256;
            int jl = f >> 5; int d = (f & 31) * 4;
            int j = k0 + jl;
            float4 v = (j < N_NODE) ? ((const float4*)(emb + (size_t)j*EMB + d))[0]
                                    : make_float4(0.f,0.f,0.f,0.f);
            ((float4*)&sh_e[jl][d])[0] = v;
        }
        __syncthreads();
        #pragma unroll
        for (int p = 0; p < 8; p++){
            int idx = tid + p * 256;
            int rl = idx >> 6, jl = idx & 63;
            int r = r0 + rl, j = k0 + jl;
            float w = 0.f;
            if (r < rows && j < N_NODE){
                float e = __expf(sh_c[rl] * sh_sv[jl] - sh_M[rl]);
                zacc[p] += e;
                w = e * adj[(size_t)r * N_NODE + j];
            }
            dacc[p] += w;
            sh_w[rl][jl] = w;
        }
        __syncthreads();
        #pragma unroll 4
        for (int jl = 0; jl < KT2; jl++){
            float4 e0 = ((const float4*)&sh_e[jl][dg*8])[0];
            float4 e1 = ((const float4*)&sh_e[jl][dg*8+4])[0];
            #pragma unroll
            for (int r = 0; r < 2; r++){
                float w = sh_w[rg*2 + r][jl];
                acc[r][0] += w*e0.x; acc[r][1] += w*e0.y;
                acc[r][2] += w*e0.z; acc[r][3] += w*e0.w;
                acc[r][4] += w*e1.x; acc[r][5] += w*e1.y;
                acc[r][6] += w*e1.z; acc[r][7] += w*e1.w;
            }
        }
    }
    int a = tid >> 6;
    #pragma unroll
    for (int p = 0; p < 8; p++){
        atomicAdd(&shZ[a + 4*p], zacc[p]);
        atomicAdd(&shD[a + 4*p], dacc[p]);
    }
    __syncthreads();
    #pragma unroll
    for (int r = 0; r < 2; r++){
        int rl = rg*2 + r; int rr = r0 + rl;
        if (rr < rows){
            float* dst = part + ((size_t)(baseR + rr) * NCH + ch) * RSTRIDE;
            ((float4*)(dst + dg*8))[0]   = make_float4(acc[r][0],acc[r][1],acc[r][2],acc[r][3]);
            ((float4*)(dst + dg*8+4))[0] = make_float4(acc[r][4],acc[r][5],acc[r][6],acc[r][7]);
        }
    }
    if (tid < RB){
        int rr = r0 + tid;
        if (rr < rows){
            float* dst = part + ((size_t)(baseR + rr) * NCH + ch) * RSTRIDE;
            dst[128] = shD[tid]; dst[129] = shZ[tid];
        }
    }
}

// small intra gate computed fully per (row, dim) thread (redundant scalar
// weights across threads — identical values, tiny K).
__device__ inline float small_gate_col(
    const float* __restrict__ adj, const float* __restrict__ matv,
    const float* __restrict__ emb, const float* __restrict__ s,
    const unsigned* __restrict__ mm2, int K, int r, int d)
{
    float c = matv[r];
    float smin = fdekey(mm2[0]), smax = fdekey(mm2[1]);
    float M = (c >= 0.f) ? c * smax : c * smin;
    float a = 0.f, dn = 0.f, Z = 0.f;
    for (int j = 0; j < K; j++){
        float e = __expf(c * s[j] - M);
        float w = e * adj[(size_t)r * K + j];
        Z += e; dn += w;
        a += w * emb[(size_t)j * EMB + d];
    }
    return a / (dn + 1e-8f * Z);
}

// phase 2 for pri/cb/cm: reduce big-gate partials + two small gates + inter.
// one row per block, 128 threads (thread = dim).
__global__ __launch_bounds__(128) void k_small_side(
    float* __restrict__ out, const float* __restrict__ e0,
    const float* __restrict__ part, int baseR,
    const float* __restrict__ adjA, const float* __restrict__ matA,
    const float* __restrict__ embA, const float* __restrict__ sA,
    const unsigned* __restrict__ mmA, int KA,
    const float* __restrict__ adjB, const float* __restrict__ matB,
    const float* __restrict__ embB, const float* __restrict__ sB,
    const unsigned* __restrict__ mmB, int KB,
    const float* __restrict__ W, const float* __restrict__ bptr)
{
    __shared__ float sh[4][EMB];
    __shared__ float shW[EMB];
    int r = blockIdx.x;
    int d = threadIdx.x;
    float num = 0.f, den = 0.f, Z = 0.f;
    for (int c = 0; c < NCH; c++){
        const float* p = part + ((size_t)(baseR + r) * NCH + c) * RSTRIDE;
        num += p[d]; den += p[128]; Z += p[129];
    }
    sh[1][d] = num / (den + 1e-8f * Z);
    sh[0][d] = e0[(size_t)r * EMB + d];
    shW[d] = W[d];
    sh[2][d] = small_gate_col(adjA, matA, embA, sA, mmA, KA, r, d);
    sh[3][d] = small_gate_col(adjB, matB, embB, sB, mmB, KB, r, d);
    __syncthreads();
    float dots[4];
    #pragma unroll
    for (int g = 0; g < 4; g++){
        float acc = 0.f;
        for (int k = 0; k < EMB; k++) acc += sh[g][k] * shW[k];
        dots[g] = acc;
    }
    float bb = bptr[0];
    float s0 = __expf(dots[0] + bb), s1 = __expf(dots[1] + bb);
    float s2 = __expf(dots[2] + bb), s3 = __expf(dots[3] + bb);
    float inv = 1.f / (s0 + s1 + s2 + s3);
    out[(size_t)r * EMB + d] =
        (s0*sh[0][d] + s1*sh[1][d] + s2*sh[2][d] + s3*sh[3][d]) * inv;
}

// ---------------------------------------------------------------------------
extern "C" void kernel_launch(void* const* d_in, const int* in_sizes, int n_in,
                              void* d_out, int out_size, void* d_ws, size_t ws_size,
                              hipStream_t stream)
{
    const int*   adj_idx  = (const int*)d_in[0];
    const float* adj_val  = (const float*)d_in[1];
    const float* a_pv   = (const float*)d_in[2];
    const float* a_vp   = (const float*)d_in[3];
    const float* a_pcb  = (const float*)d_in[4];
    const float* a_cbp  = (const float*)d_in[5];
    const float* a_cbv  = (const float*)d_in[6];
    const float* a_vcb  = (const float*)d_in[7];
    const float* a_pcm  = (const float*)d_in[8];
    const float* a_cmp  = (const float*)d_in[9];
    const float* a_cmv  = (const float*)d_in[10];
    const float* a_vcm  = (const float*)d_in[11];
    const float* a_cbcm = (const float*)d_in[12];
    const float* a_cmcb = (const float*)d_in[13];
    const float* in_item = (const float*)d_in[14];
    const float* in_pri  = (const float*)d_in[15];
    const float* in_cb   = (const float*)d_in[16];
    const float* in_cm   = (const float*)d_in[17];
    const float* m_vp  = (const float*)d_in[18];
    const float* m_vcb = (const float*)d_in[19];
    const float* m_vcm = (const float*)d_in[20];
    const float* m_pv  = (const float*)d_in[21];
    const float* m_pcb = (const float*)d_in[22];
    const float* m_pcm = (const float*)d_in[23];
    const float* m_cbp = (const float*)d_in[24];
    const float* m_cbv = (const float*)d_in[25];
    const float* m_cbcm= (const float*)d_in[26];
    const float* m_cmp = (const float*)d_in[27];
    const float* m_cmv = (const float*)d_in[28];
    const float* m_cmcb= (const float*)d_in[29];
    const float* Wi = (const float*)d_in[30]; const float* bi = (const float*)d_in[31];
    const float* Wp = (const float*)d_in[32]; const float* bp = (const float*)d_in[33];
    const float* Wcb= (const float*)d_in[34]; const float* bcb= (const float*)d_in[35];
    const float* Wcm= (const float*)d_in[36]; const float* bcm= (const float*)d_in[37];

    float* ws = (float*)d_ws;
    size_t off = 0;
    auto alloc = [&](size_t n){ float* p = ws + off; off += (n + 63) & ~(size_t)63; return p; };
    float* buf_item = alloc((size_t)N_NODE * EMB);
    float* buf_pri  = alloc((size_t)N_PRICE * EMB);
    float* buf_cb   = alloc((size_t)N_CB * EMB);
    float* buf_cm   = alloc((size_t)N_CM * EMB);
    float* s_all    = alloc(N_NODE + N_PRICE + N_CB + N_CM);
    unsigned* mm    = (unsigned*)alloc(64);
    float* g1 = alloc((size_t)N_NODE * EMB);
    float* g2 = alloc((size_t)N_NODE * EMB);
    float* g3 = alloc((size_t)N_NODE * EMB);
    float* part = g1;   // alias: partials used only after g1 is consumed

    float* out_item = (float*)d_out;
    float* out_pri  = (float*)d_out + (size_t)N_NODE * EMB;

    const float* s_v  = s_all;
    const float* s_p  = s_all + N_NODE;
    const float* s_cb = s_all + N_NODE + N_PRICE;
    const float* s_cm = s_all + N_NODE + N_PRICE + N_CB;

    const int totr = N_NODE + N_PRICE + N_CB + N_CM;

    for (int layer = 0; layer < 2; layer++){
        const float* cv  = layer ? buf_item : in_item;
        const float* cp  = layer ? buf_pri  : in_pri;
        const float* ccb = layer ? buf_cb   : in_cb;
        const float* ccm = layer ? buf_cm   : in_cm;
        float* ov = layer ? out_item : buf_item;
        float* op = layer ? out_pri  : buf_pri;

        k_rowsum<<<(totr + 3)/4, 256, 0, stream>>>(cv, cp, ccb, ccm, s_all, mm);
        k_minmax<<<(totr + 255)/256, 256, 0, stream>>>(s_all, mm);

        // V-side gates -> g1,g2,g3
        k_intra_v<<<(N_NODE + IB - 1)/IB, 256, 0, stream>>>(a_vp,  m_vp,  cp,  s_p,  mm+2, g1, N_PRICE);
        k_intra_v<<<(N_NODE + IB - 1)/IB, 256, 0, stream>>>(a_vcb, m_vcb, ccb, s_cb, mm+4, g2, N_CB);
        k_intra_v<<<(N_NODE + IB - 1)/IB, 256, 0, stream>>>(a_vcm, m_vcm, ccm, s_cm, mm+6, g3, N_CM);

        k_inter_item<<<(N_NODE + 3)/4, 256, 0, stream>>>(cv, g1, g2, g3, Wi, bi, ov);
        k_spmm<<<(NNZE + 3)/4, 256, 0, stream>>>(adj_idx, adj_idx + NNZE, adj_val, cv, ov);

        // transposed-side big gates (phase 1) — g1 is free now, reuse as partials
        k_intra_tv_partial<<<((N_PRICE + RB - 1)/RB) * NCH, 256, 0, stream>>>(
            a_pv, m_pv, cv, s_v, mm + 0, part, 0, N_PRICE);
        if (layer == 0){
            k_intra_tv_partial<<<((N_CB + RB - 1)/RB) * NCH, 256, 0, stream>>>(
                a_cbv, m_cbv, cv, s_v, mm + 0, part, N_PRICE, N_CB);
            k_intra_tv_partial<<<((N_CM + RB - 1)/RB) * NCH, 256, 0, stream>>>(
                a_cmv, m_cmv, cv, s_v, mm + 0, part, N_PRICE + N_CB, N_CM);
        }

        // phase 2 + small gates + inter for pri (and cb/cm on layer 0 only)
        k_small_side<<<N_PRICE, 128, 0, stream>>>(
            op, cp, part, 0,
            a_pcb, m_pcb, ccb, s_cb, mm+4, N_CB,
            a_pcm, m_pcm, ccm, s_cm, mm+6, N_CM,
            Wp, bp);
        if (layer == 0){
            k_small_side<<<N_CB, 128, 0, stream>>>(
                buf_cb, ccb, part, N_PRICE,
                a_cbp, m_cbp, cp, s_p, mm+2, N_PRICE,
                a_cbcm, m_cbcm, ccm, s_cm, mm+6, N_CM,
                Wcb, bcb);
            k_small_side<<<N_CM, 128, 0, stream>>>(
                buf_cm, ccm, part, N_PRICE + N_CB,
                a_cmp, m_cmp, cp, s_p, mm+2, N_PRICE,
                a_cmcb, m_cmcb, ccb, s_cb, mm+4, N_CB,
                Wcm, bcm);
        }
    }
    (void)in_sizes; (void)n_in; (void)out_size; (void)ws_size;
}

// Round 2
// 2932.968 us; speedup vs baseline: 1.4224x; 1.4224x over previous
//
#include <hip/hip_runtime.h>

#define N_NODE 50000
#define N_PRICE 100
#define N_CB 50
#define N_CM 500
#define EMB 128
#define NNZE 1000000
#define NCH 24
#define CS 2112        /* 33 tiles of 64 cols; 24*2112 = 50688 >= 50000 */
#define RSTRIDE 132    /* 128 num + den + Z + pad */
#define IB 64
#define KT 64
#define RB 32
#define KT2 64
#define SCAN_T 1024

// ---- monotone float<->uint keys for atomic min/max on floats ----
__device__ inline unsigned fkey(float f){
    unsigned b = __float_as_uint(f);
    return (b & 0x80000000u) ? ~b : (b | 0x80000000u);
}
__device__ inline float fdekey(unsigned k){
    unsigned b = (k & 0x80000000u) ? (k & 0x7fffffffu) : ~k;
    return __uint_as_float(b);
}

// ---------------------------------------------------------------------------
// rowsum: s[row] = sum over 128 dims, for all 4 node types. Also (idempotently)
// initializes the min/max slots so the next kernel's atomics have a base.
__global__ __launch_bounds__(256) void k_rowsum(
    const float* __restrict__ e_v, const float* __restrict__ e_p,
    const float* __restrict__ e_cb, const float* __restrict__ e_cm,
    float* __restrict__ s_all, unsigned* __restrict__ mm)
{
    if (blockIdx.x == 0 && threadIdx.x < 8)
        mm[threadIdx.x] = (threadIdx.x & 1) ? 0u : 0xFFFFFFFFu;
    int wid  = (blockIdx.x * 256 + threadIdx.x) >> 6;
    int lane = threadIdx.x & 63;
    const int NT = N_NODE + N_PRICE + N_CB + N_CM;
    if (wid >= NT) return;
    const float* src; int lr;
    if (wid < N_NODE)                { src = e_v;  lr = wid; }
    else if (wid < N_NODE+N_PRICE)   { src = e_p;  lr = wid - N_NODE; }
    else if (wid < N_NODE+N_PRICE+N_CB){ src = e_cb; lr = wid - N_NODE - N_PRICE; }
    else                             { src = e_cm; lr = wid - N_NODE - N_PRICE - N_CB; }
    float2 v = ((const float2*)(src + (size_t)lr * EMB))[lane];
    float sum = v.x + v.y;
    #pragma unroll
    for (int o = 32; o > 0; o >>= 1) sum += __shfl_down(sum, o, 64);
    if (lane == 0) s_all[wid] = sum;
}

// min/max of s per type (block pre-reduce in LDS, then global atomics)
__global__ __launch_bounds__(256) void k_minmax(
    const float* __restrict__ s_all, unsigned* __restrict__ mm)
{
    __shared__ unsigned smin[4], smax[4];
    int t = threadIdx.x;
    if (t < 4){ smin[t] = 0xFFFFFFFFu; smax[t] = 0u; }
    __syncthreads();
    int gid = blockIdx.x * 256 + t;
    const int NT = N_NODE + N_PRICE + N_CB + N_CM;
    if (gid < NT){
        int ty = (gid < N_NODE) ? 0 :
                 (gid < N_NODE+N_PRICE) ? 1 :
                 (gid < N_NODE+N_PRICE+N_CB) ? 2 : 3;
        unsigned k = fkey(s_all[gid]);
        atomicMin(&smin[ty], k);
        atomicMax(&smax[ty], k);
    }
    __syncthreads();
    if (t < 4){
        if (smin[t] != 0xFFFFFFFFu) atomicMin(&mm[2*t],   smin[t]);
        if (smax[t] != 0u)          atomicMax(&mm[2*t+1], smax[t]);
    }
}

// ---------------------------------------------------------------------------
// CSR build: histogram -> scan -> scatter. Built ONCE per call, used twice.
__global__ __launch_bounds__(256) void k_hist(
    const int* __restrict__ rows, int* __restrict__ counts)
{
    int i = blockIdx.x * 256 + threadIdx.x;
    if (i < NNZE) atomicAdd(&counts[rows[i]], 1);
}

__global__ __launch_bounds__(SCAN_T) void k_scan(
    const int* __restrict__ counts, int* __restrict__ offs, int* __restrict__ cursor)
{
    __shared__ int part[SCAN_T];
    int t = threadIdx.x;
    const int CHUNK = (N_NODE + SCAN_T - 1) / SCAN_T;
    int base = t * CHUNK;
    int s = 0;
    for (int i = 0; i < CHUNK; i++){
        int idx = base + i;
        if (idx < N_NODE) s += counts[idx];
    }
    part[t] = s;
    __syncthreads();
    for (int o = 1; o < SCAN_T; o <<= 1){
        int u = (t >= o) ? part[t - o] : 0;
        __syncthreads();
        part[t] += u;
        __syncthreads();
    }
    int run = part[t] - s;    // exclusive base for this chunk
    for (int i = 0; i < CHUNK; i++){
        int idx = base + i;
        if (idx < N_NODE){
            offs[idx] = run; cursor[idx] = run;
            run += counts[idx];
        }
    }
    if (t == SCAN_T - 1) offs[N_NODE] = run;
}

__global__ __launch_bounds__(256) void k_scatter(
    const int* __restrict__ rows, const int* __restrict__ cols,
    const float* __restrict__ vals, int* __restrict__ cursor,
    int* __restrict__ scol, float* __restrict__ sval)
{
    int i = blockIdx.x * 256 + threadIdx.x;
    if (i < NNZE){
        int r = rows[i];
        int p = atomicAdd(&cursor[r], 1);
        scol[p] = cols[i];
        sval[p] = vals[i];
    }
}

// CSR spmm: one wave per row; lanes cooperatively load nnz, broadcast via shfl,
// accumulate float2 in registers, single non-atomic read-add-write of out row.
__global__ __launch_bounds__(256) void k_spmm_csr(
    const int* __restrict__ offs, const int* __restrict__ scol,
    const float* __restrict__ sval, const float* __restrict__ emb,
    float* __restrict__ out)
{
    int row  = (blockIdx.x * 256 + threadIdx.x) >> 6;
    int lane = threadIdx.x & 63;
    if (row >= N_NODE) return;
    int s = offs[row], e = offs[row + 1];
    float2 acc = make_float2(0.f, 0.f);
    for (int base = s; base < e; base += 64){
        int n = base + lane;
        int   cl = (n < e) ? scol[n] : 0;
        float vl = (n < e) ? sval[n] : 0.f;
        int m = e - base; if (m > 64) m = 64;
        for (int j = 0; j < m; j++){
            int   c = __shfl(cl, j, 64);
            float v = __shfl(vl, j, 64);
            float2 em = *(const float2*)(emb + (size_t)c * EMB + lane * 2);
            acc.x += v * em.x; acc.y += v * em.y;
        }
    }
    float* dst = out + (size_t)row * EMB + lane * 2;
    float2 o = *(float2*)dst;
    o.x += acc.x; o.y += acc.y;
    *(float2*)dst = o;
}

// ---------------------------------------------------------------------------
// V-side intra gate: out[i,:] = sum_j w_ij emb2[j,:] / (den_i + 1e-8 Z_i)
__global__ __launch_bounds__(256) void k_intra_v(
    const float* __restrict__ adj, const float* __restrict__ matv,
    const float* __restrict__ emb2, const float* __restrict__ s_src,
    const unsigned* __restrict__ mm2, float* __restrict__ out, int K)
{
    __shared__ float sh_s[512];
    __shared__ float sh_c[IB], sh_M[IB], sh_inv[IB];
    __shared__ float sh_w[IB][KT + 1];
    __shared__ float sh_e[KT][EMB];
    int tid = threadIdx.x;
    int i0  = blockIdx.x * IB;

    for (int j = tid; j < K; j += 256) sh_s[j] = s_src[j];
    if (tid < IB){
        int i = i0 + tid;
        float c = (i < N_NODE) ? matv[i] : 0.f;
        float smin = fdekey(mm2[0]), smax = fdekey(mm2[1]);
        sh_c[tid] = c;
        sh_M[tid] = (c >= 0.f) ? c * smax : c * smin;
    }
    __syncthreads();

    float Z = 0.f, den = 0.f;
    if (tid < IB){
        float c = sh_c[tid], M = sh_M[tid];
        for (int j = 0; j < K; j++) Z += __expf(c * sh_s[j] - M);
    }

    float acc[4][8];
    #pragma unroll
    for (int r = 0; r < 4; r++)
        #pragma unroll
        for (int d = 0; d < 8; d++) acc[r][d] = 0.f;
    int dg = tid & 15, rg = tid >> 4;

    int ntile = (K + KT - 1) / KT;
    for (int t = 0; t < ntile; t++){
        int k0 = t * KT;
        __syncthreads();
        #pragma unroll
        for (int q = 0; q < 8; q++){
            int f  = tid + q * 256;
            int jl = f >> 5;
            int d  = (f & 31) * 4;
            int j  = k0 + jl;
            float4 v = (j < K) ? ((const float4*)(emb2 + (size_t)j * EMB + d))[0]
                               : make_float4(0.f,0.f,0.f,0.f);
            ((float4*)&sh_e[jl][d])[0] = v;
        }
        #pragma unroll
        for (int p = 0; p < 16; p++){
            int idx = tid + p * 256;
            int rl = idx >> 6, jl = idx & 63;
            int i = i0 + rl, j = k0 + jl;
            float w = 0.f;
            if (j < K && i < N_NODE){
                float e = __expf(sh_c[rl] * sh_s[j] - sh_M[rl]);
                w = e * adj[(size_t)i * K + j];
            }
            sh_w[rl][jl] = w;
        }
        __syncthreads();
        if (tid < IB){
            float d0 = 0.f;
            #pragma unroll 8
            for (int jl = 0; jl < KT; jl++) d0 += sh_w[tid][jl];
            den += d0;
        }
        #pragma unroll 4
        for (int jl = 0; jl < KT; jl++){
            float4 e0 = ((const float4*)&sh_e[jl][dg*8])[0];
            float4 e1 = ((const float4*)&sh_e[jl][dg*8+4])[0];
            #pragma unroll
            for (int r = 0; r < 4; r++){
                float w = sh_w[rg*4 + r][jl];
                acc[r][0] += w*e0.x; acc[r][1] += w*e0.y;
                acc[r][2] += w*e0.z; acc[r][3] += w*e0.w;
                acc[r][4] += w*e1.x; acc[r][5] += w*e1.y;
                acc[r][6] += w*e1.z; acc[r][7] += w*e1.w;
            }
        }
    }
    __syncthreads();
    if (tid < IB) sh_inv[tid] = 1.f / (den + 1e-8f * Z);
    __syncthreads();
    #pragma unroll
    for (int r = 0; r < 4; r++){
        int i = i0 + rg*4 + r;
        if (i < N_NODE){
            float inv = sh_inv[rg*4 + r];
            ((float4*)(out + (size_t)i*EMB + dg*8))[0] =
                make_float4(acc[r][0]*inv, acc[r][1]*inv, acc[r][2]*inv, acc[r][3]*inv);
            ((float4*)(out + (size_t)i*EMB + dg*8 + 4))[0] =
                make_float4(acc[r][4]*inv, acc[r][5]*inv, acc[r][6]*inv, acc[r][7]*inv);
        }
    }
}

// ---------------------------------------------------------------------------
// inter gate for items: one wave per row; 4 shuffle-reduced dots with W.
__global__ __launch_bounds__(256) void k_inter_item(
    const float* __restrict__ e0, const float* __restrict__ g1,
    const float* __restrict__ g2, const float* __restrict__ g3,
    const float* __restrict__ W, const float* __restrict__ b,
    float* __restrict__ out)
{
    int wid  = (blockIdx.x * 256 + threadIdx.x) >> 6;
    int lane = threadIdx.x & 63;
    if (wid >= N_NODE) return;
    size_t base = (size_t)wid * EMB + lane * 2;
    float2 v0 = *(const float2*)(e0 + base);
    float2 v1 = *(const float2*)(g1 + base);
    float2 v2 = *(const float2*)(g2 + base);
    float2 v3 = *(const float2*)(g3 + base);
    float2 w2 = *(const float2*)(W + lane * 2);
    float d0 = v0.x*w2.x + v0.y*w2.y;
    float d1 = v1.x*w2.x + v1.y*w2.y;
    float d2 = v2.x*w2.x + v2.y*w2.y;
    float d3 = v3.x*w2.x + v3.y*w2.y;
    #pragma unroll
    for (int o = 32; o > 0; o >>= 1){
        d0 += __shfl_xor(d0, o, 64); d1 += __shfl_xor(d1, o, 64);
        d2 += __shfl_xor(d2, o, 64); d3 += __shfl_xor(d3, o, 64);
    }
    float bb = b[0];
    float s0 = __expf(d0 + bb), s1 = __expf(d1 + bb);
    float s2 = __expf(d2 + bb), s3 = __expf(d3 + bb);
    float inv = 1.f / (s0 + s1 + s2 + s3);
    float2 o2;
    o2.x = (s0*v0.x + s1*v1.x + s2*v2.x + s3*v3.x) * inv;
    o2.y = (s0*v0.y + s1*v1.y + s2*v2.y + s3*v3.y) * inv;
    *(float2*)(out + base) = o2;
}

// ---------------------------------------------------------------------------
// transposed-side intra gate, phase 1: partial (num[128], den, Z) per
// (row, chunk). RB=32 rows/block, chunk = CS cols staged in KT2-col tiles.
__global__ __launch_bounds__(256) void k_intra_tv_partial(
    const float* __restrict__ adj, const float* __restrict__ matv,
    const float* __restrict__ emb, const float* __restrict__ s_v,
    const unsigned* __restrict__ mm2,
    float* __restrict__ part, int baseR, int rows)
{
    __shared__ float sh_c[RB], sh_M[RB];
    __shared__ float sh_sv[KT2];
    __shared__ float sh_w[RB][KT2 + 1];
    __shared__ float sh_e[KT2][EMB];
    __shared__ float shZ[RB], shD[RB];
    int tid = threadIdx.x;
    int rb = blockIdx.x / NCH;
    int ch = blockIdx.x % NCH;
    int r0 = rb * RB;
    if (tid < RB){
        int r = r0 + tid;
        float c = (r < rows) ? matv[r] : 0.f;
        float smin = fdekey(mm2[0]), smax = fdekey(mm2[1]);
        sh_c[tid] = c;
        sh_M[tid] = (c >= 0.f) ? c * smax : c * smin;
        shZ[tid] = 0.f; shD[tid] = 0.f;
    }
    float zacc[8], dacc[8];
    #pragma unroll
    for (int p = 0; p < 8; p++){ zacc[p] = 0.f; dacc[p] = 0.f; }
    float acc[2][8];
    #pragma unroll
    for (int r = 0; r < 2; r++)
        #pragma unroll
        for (int d = 0; d < 8; d++) acc[r][d] = 0.f;
    int dg = tid & 15, rg = tid >> 4;
    int j0 = ch * CS;
    __syncthreads();

    for (int t = 0; t < CS / KT2; t++){
        int k0 = j0 + t * KT2;
        __syncthreads();
        if (tid < KT2) sh_sv[tid] = (k0 + tid < N_NODE) ? s_v[k0 + tid] : 0.f;
        #pragma unroll
        for (int q = 0; q < 8; q++){
            int f = tid + q * 256;
            int jl = f >> 5; int d = (f & 31) * 4;
            int j = k0 + jl;
            float4 v = (j < N_NODE) ? ((const float4*)(emb + (size_t)j*EMB + d))[0]
                                    : make_float4(0.f,0.f,0.f,0.f);
            ((float4*)&sh_e[jl][d])[0] = v;
        }
        __syncthreads();
        #pragma unroll
        for (int p = 0; p < 8; p++){
            int idx = tid + p * 256;
            int rl = idx >> 6, jl = idx & 63;
            int r = r0 + rl, j = k0 + jl;
            float w = 0.f;
            if (r < rows && j < N_NODE){
                float e = __expf(sh_c[rl] * sh_sv[jl] - sh_M[rl]);
                zacc[p] += e;
                w = e * adj[(size_t)r * N_NODE + j];
            }
            dacc[p] += w;
            sh_w[rl][jl] = w;
        }
        __syncthreads();
        #pragma unroll 4
        for (int jl = 0; jl < KT2; jl++){
            float4 e0 = ((const float4*)&sh_e[jl][dg*8])[0];
            float4 e1 = ((const float4*)&sh_e[jl][dg*8+4])[0];
            #pragma unroll
            for (int r = 0; r < 2; r++){
                float w = sh_w[rg*2 + r][jl];
                acc[r][0] += w*e0.x; acc[r][1] += w*e0.y;
                acc[r][2] += w*e0.z; acc[r][3] += w*e0.w;
                acc[r][4] += w*e1.x; acc[r][5] += w*e1.y;
                acc[r][6] += w*e1.z; acc[r][7] += w*e1.w;
            }
        }
    }
    int a = tid >> 6;
    #pragma unroll
    for (int p = 0; p < 8; p++){
        atomicAdd(&shZ[a + 4*p], zacc[p]);
        atomicAdd(&shD[a + 4*p], dacc[p]);
    }
    __syncthreads();
    #pragma unroll
    for (int r = 0; r < 2; r++){
        int rl = rg*2 + r; int rr = r0 + rl;
        if (rr < rows){
            float* dst = part + ((size_t)(baseR + rr) * NCH + ch) * RSTRIDE;
            ((float4*)(dst + dg*8))[0]   = make_float4(acc[r][0],acc[r][1],acc[r][2],acc[r][3]);
            ((float4*)(dst + dg*8+4))[0] = make_float4(acc[r][4],acc[r][5],acc[r][6],acc[r][7]);
        }
    }
    if (tid < RB){
        int rr = r0 + tid;
        if (rr < rows){
            float* dst = part + ((size_t)(baseR + rr) * NCH + ch) * RSTRIDE;
            dst[128] = shD[tid]; dst[129] = shZ[tid];
        }
    }
}

// small intra gate computed fully per (row, dim) thread
__device__ inline float small_gate_col(
    const float* __restrict__ adj, const float* __restrict__ matv,
    const float* __restrict__ emb, const float* __restrict__ s,
    const unsigned* __restrict__ mm2, int K, int r, int d)
{
    float c = matv[r];
    float smin = fdekey(mm2[0]), smax = fdekey(mm2[1]);
    float M = (c >= 0.f) ? c * smax : c * smin;
    float a = 0.f, dn = 0.f, Z = 0.f;
    for (int j = 0; j < K; j++){
        float e = __expf(c * s[j] - M);
        float w = e * adj[(size_t)r * K + j];
        Z += e; dn += w;
        a += w * emb[(size_t)j * EMB + d];
    }
    return a / (dn + 1e-8f * Z);
}

// phase 2 for pri/cb/cm: reduce big-gate partials + two small gates + inter.
__global__ __launch_bounds__(128) void k_small_side(
    float* __restrict__ out, const float* __restrict__ e0,
    const float* __restrict__ part, int baseR,
    const float* __restrict__ adjA, const float* __restrict__ matA,
    const float* __restrict__ embA, const float* __restrict__ sA,
    const unsigned* __restrict__ mmA, int KA,
    const float* __restrict__ adjB, const float* __restrict__ matB,
    const float* __restrict__ embB, const float* __restrict__ sB,
    const unsigned* __restrict__ mmB, int KB,
    const float* __restrict__ W, const float* __restrict__ bptr)
{
    __shared__ float sh[4][EMB];
    __shared__ float shW[EMB];
    int r = blockIdx.x;
    int d = threadIdx.x;
    float num = 0.f, den = 0.f, Z = 0.f;
    for (int c = 0; c < NCH; c++){
        const float* p = part + ((size_t)(baseR + r) * NCH + c) * RSTRIDE;
        num += p[d]; den += p[128]; Z += p[129];
    }
    sh[1][d] = num / (den + 1e-8f * Z);
    sh[0][d] = e0[(size_t)r * EMB + d];
    shW[d] = W[d];
    sh[2][d] = small_gate_col(adjA, matA, embA, sA, mmA, KA, r, d);
    sh[3][d] = small_gate_col(adjB, matB, embB, sB, mmB, KB, r, d);
    __syncthreads();
    float dots[4];
    #pragma unroll
    for (int g = 0; g < 4; g++){
        float acc = 0.f;
        for (int k = 0; k < EMB; k++) acc += sh[g][k] * shW[k];
        dots[g] = acc;
    }
    float bb = bptr[0];
    float s0 = __expf(dots[0] + bb), s1 = __expf(dots[1] + bb);
    float s2 = __expf(dots[2] + bb), s3 = __expf(dots[3] + bb);
    float inv = 1.f / (s0 + s1 + s2 + s3);
    out[(size_t)r * EMB + d] =
        (s0*sh[0][d] + s1*sh[1][d] + s2*sh[2][d] + s3*sh[3][d]) * inv;
}

// ---------------------------------------------------------------------------
extern "C" void kernel_launch(void* const* d_in, const int* in_sizes, int n_in,
                              void* d_out, int out_size, void* d_ws, size_t ws_size,
                              hipStream_t stream)
{
    const int*   adj_idx  = (const int*)d_in[0];
    const float* adj_val  = (const float*)d_in[1];
    const float* a_pv   = (const float*)d_in[2];
    const float* a_vp   = (const float*)d_in[3];
    const float* a_pcb  = (const float*)d_in[4];
    const float* a_cbp  = (const float*)d_in[5];
    const float* a_cbv  = (const float*)d_in[6];
    const float* a_vcb  = (const float*)d_in[7];
    const float* a_pcm  = (const float*)d_in[8];
    const float* a_cmp  = (const float*)d_in[9];
    const float* a_cmv  = (const float*)d_in[10];
    const float* a_vcm  = (const float*)d_in[11];
    const float* a_cbcm = (const float*)d_in[12];
    const float* a_cmcb = (const float*)d_in[13];
    const float* in_item = (const float*)d_in[14];
    const float* in_pri  = (const float*)d_in[15];
    const float* in_cb   = (const float*)d_in[16];
    const float* in_cm   = (const float*)d_in[17];
    const float* m_vp  = (const float*)d_in[18];
    const float* m_vcb = (const float*)d_in[19];
    const float* m_vcm = (const float*)d_in[20];
    const float* m_pv  = (const float*)d_in[21];
    const float* m_pcb = (const float*)d_in[22];
    const float* m_pcm = (const float*)d_in[23];
    const float* m_cbp = (const float*)d_in[24];
    const float* m_cbv = (const float*)d_in[25];
    const float* m_cbcm= (const float*)d_in[26];
    const float* m_cmp = (const float*)d_in[27];
    const float* m_cmv = (const float*)d_in[28];
    const float* m_cmcb= (const float*)d_in[29];
    const float* Wi = (const float*)d_in[30]; const float* bi = (const float*)d_in[31];
    const float* Wp = (const float*)d_in[32]; const float* bp = (const float*)d_in[33];
    const float* Wcb= (const float*)d_in[34]; const float* bcb= (const float*)d_in[35];
    const float* Wcm= (const float*)d_in[36]; const float* bcm= (const float*)d_in[37];

    float* ws = (float*)d_ws;
    size_t off = 0;
    auto alloc = [&](size_t n){ float* p = ws + off; off += (n + 63) & ~(size_t)63; return p; };
    float* buf_item = alloc((size_t)N_NODE * EMB);
    float* buf_pri  = alloc((size_t)N_PRICE * EMB);
    float* buf_cb   = alloc((size_t)N_CB * EMB);
    float* buf_cm   = alloc((size_t)N_CM * EMB);
    float* s_all    = alloc(N_NODE + N_PRICE + N_CB + N_CM);
    unsigned* mm    = (unsigned*)alloc(64);
    float* g1 = alloc((size_t)N_NODE * EMB);
    float* g2 = alloc((size_t)N_NODE * EMB);
    float* g3 = alloc((size_t)N_NODE * EMB);
    float* part = g1;   // alias: partials used only after g1 is consumed
    int*   counts = (int*)alloc(N_NODE + 64);
    int*   offs   = (int*)alloc(N_NODE + 64);
    int*   cursor = (int*)alloc(N_NODE + 64);
    int*   scol   = (int*)alloc(NNZE);
    float* sval   = alloc(NNZE);

    float* out_item = (float*)d_out;
    float* out_pri  = (float*)d_out + (size_t)N_NODE * EMB;

    const float* s_v  = s_all;
    const float* s_p  = s_all + N_NODE;
    const float* s_cb = s_all + N_NODE + N_PRICE;
    const float* s_cm = s_all + N_NODE + N_PRICE + N_CB;

    const int totr = N_NODE + N_PRICE + N_CB + N_CM;

    // ---- CSR build (once; adjacency is layer-invariant) ----
    hipMemsetAsync(counts, 0, N_NODE * sizeof(int), stream);
    k_hist<<<(NNZE + 255)/256, 256, 0, stream>>>(adj_idx, counts);
    k_scan<<<1, SCAN_T, 0, stream>>>(counts, offs, cursor);
    k_scatter<<<(NNZE + 255)/256, 256, 0, stream>>>(adj_idx, adj_idx + NNZE,
                                                    adj_val, cursor, scol, sval);

    for (int layer = 0; layer < 2; layer++){
        const float* cv  = layer ? buf_item : in_item;
        const float* cp  = layer ? buf_pri  : in_pri;
        const float* ccb = layer ? buf_cb   : in_cb;
        const float* ccm = layer ? buf_cm   : in_cm;
        float* ov = layer ? out_item : buf_item;
        float* op = layer ? out_pri  : buf_pri;

        k_rowsum<<<(totr + 3)/4, 256, 0, stream>>>(cv, cp, ccb, ccm, s_all, mm);
        k_minmax<<<(totr + 255)/256, 256, 0, stream>>>(s_all, mm);

        // V-side gates -> g1,g2,g3
        k_intra_v<<<(N_NODE + IB - 1)/IB, 256, 0, stream>>>(a_vp,  m_vp,  cp,  s_p,  mm+2, g1, N_PRICE);
        k_intra_v<<<(N_NODE + IB - 1)/IB, 256, 0, stream>>>(a_vcb, m_vcb, ccb, s_cb, mm+4, g2, N_CB);
        k_intra_v<<<(N_NODE + IB - 1)/IB, 256, 0, stream>>>(a_vcm, m_vcm, ccm, s_cm, mm+6, g3, N_CM);

        k_inter_item<<<(N_NODE + 3)/4, 256, 0, stream>>>(cv, g1, g2, g3, Wi, bi, ov);
        k_spmm_csr<<<(N_NODE*64 + 255)/256, 256, 0, stream>>>(offs, scol, sval, cv, ov);

        // transposed-side big gates (phase 1) — g1 is free now, reuse as partials
        k_intra_tv_partial<<<((N_PRICE + RB - 1)/RB) * NCH, 256, 0, stream>>>(
            a_pv, m_pv, cv, s_v, mm + 0, part, 0, N_PRICE);
        if (layer == 0){
            k_intra_tv_partial<<<((N_CB + RB - 1)/RB) * NCH, 256, 0, stream>>>(
                a_cbv, m_cbv, cv, s_v, mm + 0, part, N_PRICE, N_CB);
            k_intra_tv_partial<<<((N_CM + RB - 1)/RB) * NCH, 256, 0, stream>>>(
                a_cmv, m_cmv, cv, s_v, mm + 0, part, N_PRICE + N_CB, N_CM);
        }

        // phase 2 + small gates + inter for pri (and cb/cm on layer 0 only)
        k_small_side<<<N_PRICE, 128, 0, stream>>>(
            op, cp, part, 0,
            a_pcb, m_pcb, ccb, s_cb, mm+4, N_CB,
            a_pcm, m_pcm, ccm, s_cm, mm+6, N_CM,
            Wp, bp);
        if (layer == 0){
            k_small_side<<<N_CB, 128, 0, stream>>>(
                buf_cb, ccb, part, N_PRICE,
                a_cbp, m_cbp, cp, s_p, mm+2, N_PRICE,
                a_cbcm, m_cbcm, ccm, s_cm, mm+6, N_CM,
                Wcb, bcb);
            k_small_side<<<N_CM, 128, 0, stream>>>(
                buf_cm, ccm, part, N_PRICE + N_CB,
                a_cmp, m_cmp, cp, s_p, mm+2, N_PRICE,
                a_cmcb, m_cmcb, ccb, s_cb, mm+4, N_CB,
                Wcm, bcm);
        }
    }
    (void)in_sizes; (void)n_in; (void)out_size; (void)ws_size;
}

// Round 3
// 2385.182 us; speedup vs baseline: 1.7491x; 1.2297x over previous
//
#include <hip/hip_runtime.h>

#define N_NODE 50000
#define N_PRICE 100
#define N_CB 50
#define N_CM 500
#define EMB 128
#define NNZE 1000000
#define NCH 96
#define CS 576         /* 9 tiles of 64 cols; 96*576 = 55296 >= 50000 */
#define RSTRIDE 132    /* 128 num + den + Z + pad */
#define IB 64
#define KT 64
#define RB 32
#define KT2 64
#define SCAN_T 1024

// ---- monotone float<->uint keys for atomic min/max on floats ----
__device__ inline unsigned fkey(float f){
    unsigned b = __float_as_uint(f);
    return (b & 0x80000000u) ? ~b : (b | 0x80000000u);
}
__device__ inline float fdekey(unsigned k){
    unsigned b = (k & 0x80000000u) ? (k & 0x7fffffffu) : ~k;
    return __uint_as_float(b);
}

// ---------------------------------------------------------------------------
__global__ __launch_bounds__(256) void k_rowsum(
    const float* __restrict__ e_v, const float* __restrict__ e_p,
    const float* __restrict__ e_cb, const float* __restrict__ e_cm,
    float* __restrict__ s_all, unsigned* __restrict__ mm)
{
    if (blockIdx.x == 0 && threadIdx.x < 8)
        mm[threadIdx.x] = (threadIdx.x & 1) ? 0u : 0xFFFFFFFFu;
    int wid  = (blockIdx.x * 256 + threadIdx.x) >> 6;
    int lane = threadIdx.x & 63;
    const int NT = N_NODE + N_PRICE + N_CB + N_CM;
    if (wid >= NT) return;
    const float* src; int lr;
    if (wid < N_NODE)                { src = e_v;  lr = wid; }
    else if (wid < N_NODE+N_PRICE)   { src = e_p;  lr = wid - N_NODE; }
    else if (wid < N_NODE+N_PRICE+N_CB){ src = e_cb; lr = wid - N_NODE - N_PRICE; }
    else                             { src = e_cm; lr = wid - N_NODE - N_PRICE - N_CB; }
    float2 v = ((const float2*)(src + (size_t)lr * EMB))[lane];
    float sum = v.x + v.y;
    #pragma unroll
    for (int o = 32; o > 0; o >>= 1) sum += __shfl_down(sum, o, 64);
    if (lane == 0) s_all[wid] = sum;
}

__global__ __launch_bounds__(256) void k_minmax(
    const float* __restrict__ s_all, unsigned* __restrict__ mm)
{
    __shared__ unsigned smin[4], smax[4];
    int t = threadIdx.x;
    if (t < 4){ smin[t] = 0xFFFFFFFFu; smax[t] = 0u; }
    __syncthreads();
    int gid = blockIdx.x * 256 + t;
    const int NT = N_NODE + N_PRICE + N_CB + N_CM;
    if (gid < NT){
        int ty = (gid < N_NODE) ? 0 :
                 (gid < N_NODE+N_PRICE) ? 1 :
                 (gid < N_NODE+N_PRICE+N_CB) ? 2 : 3;
        unsigned k = fkey(s_all[gid]);
        atomicMin(&smin[ty], k);
        atomicMax(&smax[ty], k);
    }
    __syncthreads();
    if (t < 4){
        if (smin[t] != 0xFFFFFFFFu) atomicMin(&mm[2*t],   smin[t]);
        if (smax[t] != 0u)          atomicMax(&mm[2*t+1], smax[t]);
    }
}

// ---------------------------------------------------------------------------
// CSR build: histogram -> scan -> scatter. Built ONCE per call, used twice.
__global__ __launch_bounds__(256) void k_hist(
    const int* __restrict__ rows, int* __restrict__ counts)
{
    int i = blockIdx.x * 256 + threadIdx.x;
    if (i < NNZE) atomicAdd(&counts[rows[i]], 1);
}

__global__ __launch_bounds__(SCAN_T) void k_scan(
    const int* __restrict__ counts, int* __restrict__ offs, int* __restrict__ cursor)
{
    __shared__ int part[SCAN_T];
    int t = threadIdx.x;
    const int CHUNK = (N_NODE + SCAN_T - 1) / SCAN_T;
    int base = t * CHUNK;
    int s = 0;
    for (int i = 0; i < CHUNK; i++){
        int idx = base + i;
        if (idx < N_NODE) s += counts[idx];
    }
    part[t] = s;
    __syncthreads();
    for (int o = 1; o < SCAN_T; o <<= 1){
        int u = (t >= o) ? part[t - o] : 0;
        __syncthreads();
        part[t] += u;
        __syncthreads();
    }
    int run = part[t] - s;
    for (int i = 0; i < CHUNK; i++){
        int idx = base + i;
        if (idx < N_NODE){
            offs[idx] = run; cursor[idx] = run;
            run += counts[idx];
        }
    }
    if (t == SCAN_T - 1) offs[N_NODE] = run;
}

__global__ __launch_bounds__(256) void k_scatter(
    const int* __restrict__ rows, const int* __restrict__ cols,
    const float* __restrict__ vals, int* __restrict__ cursor,
    int* __restrict__ scol, float* __restrict__ sval)
{
    int i = blockIdx.x * 256 + threadIdx.x;
    if (i < NNZE){
        int r = rows[i];
        int p = atomicAdd(&cursor[r], 1);
        scol[p] = cols[i];
        sval[p] = vals[i];
    }
}

// CSR spmm: one wave per row; lanes cooperatively load nnz, broadcast via shfl.
__global__ __launch_bounds__(256) void k_spmm_csr(
    const int* __restrict__ offs, const int* __restrict__ scol,
    const float* __restrict__ sval, const float* __restrict__ emb,
    float* __restrict__ out)
{
    int row  = (blockIdx.x * 256 + threadIdx.x) >> 6;
    int lane = threadIdx.x & 63;
    if (row >= N_NODE) return;
    int s = offs[row], e = offs[row + 1];
    float2 acc = make_float2(0.f, 0.f);
    for (int base = s; base < e; base += 64){
        int n = base + lane;
        int   cl = (n < e) ? scol[n] : 0;
        float vl = (n < e) ? sval[n] : 0.f;
        int m = e - base; if (m > 64) m = 64;
        for (int j = 0; j < m; j++){
            int   c = __shfl(cl, j, 64);
            float v = __shfl(vl, j, 64);
            float2 em = *(const float2*)(emb + (size_t)c * EMB + lane * 2);
            acc.x += v * em.x; acc.y += v * em.y;
        }
    }
    float* dst = out + (size_t)row * EMB + lane * 2;
    float2 o = *(float2*)dst;
    o.x += acc.x; o.y += acc.y;
    *(float2*)dst = o;
}

// ---------------------------------------------------------------------------
// V-side intra gate. FMA-loop reads use stride-4-word pattern (dims dg*4 and
// 64+dg*4) -> 2 lanes/bank = conflict-free (m136).
__global__ __launch_bounds__(256) void k_intra_v(
    const float* __restrict__ adj, const float* __restrict__ matv,
    const float* __restrict__ emb2, const float* __restrict__ s_src,
    const unsigned* __restrict__ mm2, float* __restrict__ out, int K)
{
    __shared__ float sh_s[512];
    __shared__ float sh_c[IB], sh_M[IB], sh_inv[IB];
    __shared__ float sh_w[IB][KT + 1];
    __shared__ float sh_e[KT][EMB];
    int tid = threadIdx.x;
    int i0  = blockIdx.x * IB;

    for (int j = tid; j < K; j += 256) sh_s[j] = s_src[j];
    if (tid < IB){
        int i = i0 + tid;
        float c = (i < N_NODE) ? matv[i] : 0.f;
        float smin = fdekey(mm2[0]), smax = fdekey(mm2[1]);
        sh_c[tid] = c;
        sh_M[tid] = (c >= 0.f) ? c * smax : c * smin;
    }
    __syncthreads();

    float Z = 0.f, den = 0.f;
    if (tid < IB){
        float c = sh_c[tid], M = sh_M[tid];
        for (int j = 0; j < K; j++) Z += __expf(c * sh_s[j] - M);
    }

    float acc[4][8];
    #pragma unroll
    for (int r = 0; r < 4; r++)
        #pragma unroll
        for (int d = 0; d < 8; d++) acc[r][d] = 0.f;
    int dg = tid & 15, rg = tid >> 4;

    int ntile = (K + KT - 1) / KT;
    for (int t = 0; t < ntile; t++){
        int k0 = t * KT;
        __syncthreads();
        #pragma unroll
        for (int q = 0; q < 8; q++){
            int f  = tid + q * 256;
            int jl = f >> 5;
            int d  = (f & 31) * 4;
            int j  = k0 + jl;
            float4 v = (j < K) ? ((const float4*)(emb2 + (size_t)j * EMB + d))[0]
                               : make_float4(0.f,0.f,0.f,0.f);
            ((float4*)&sh_e[jl][d])[0] = v;
        }
        #pragma unroll
        for (int p = 0; p < 16; p++){
            int idx = tid + p * 256;
            int rl = idx >> 6, jl = idx & 63;
            int i = i0 + rl, j = k0 + jl;
            float w = 0.f;
            if (j < K && i < N_NODE){
                float e = __expf(sh_c[rl] * sh_s[j] - sh_M[rl]);
                w = e * adj[(size_t)i * K + j];
            }
            sh_w[rl][jl] = w;
        }
        __syncthreads();
        if (tid < IB){
            float d0 = 0.f;
            #pragma unroll 8
            for (int jl = 0; jl < KT; jl++) d0 += sh_w[tid][jl];
            den += d0;
        }
        #pragma unroll 4
        for (int jl = 0; jl < KT; jl++){
            float4 e0 = ((const float4*)&sh_e[jl][dg*4])[0];
            float4 e1 = ((const float4*)&sh_e[jl][64 + dg*4])[0];
            #pragma unroll
            for (int r = 0; r < 4; r++){
                float w = sh_w[rg*4 + r][jl];
                acc[r][0] += w*e0.x; acc[r][1] += w*e0.y;
                acc[r][2] += w*e0.z; acc[r][3] += w*e0.w;
                acc[r][4] += w*e1.x; acc[r][5] += w*e1.y;
                acc[r][6] += w*e1.z; acc[r][7] += w*e1.w;
            }
        }
    }
    __syncthreads();
    if (tid < IB) sh_inv[tid] = 1.f / (den + 1e-8f * Z);
    __syncthreads();
    #pragma unroll
    for (int r = 0; r < 4; r++){
        int i = i0 + rg*4 + r;
        if (i < N_NODE){
            float inv = sh_inv[rg*4 + r];
            ((float4*)(out + (size_t)i*EMB + dg*4))[0] =
                make_float4(acc[r][0]*inv, acc[r][1]*inv, acc[r][2]*inv, acc[r][3]*inv);
            ((float4*)(out + (size_t)i*EMB + 64 + dg*4))[0] =
                make_float4(acc[r][4]*inv, acc[r][5]*inv, acc[r][6]*inv, acc[r][7]*inv);
        }
    }
}

// ---------------------------------------------------------------------------
__global__ __launch_bounds__(256) void k_inter_item(
    const float* __restrict__ e0, const float* __restrict__ g1,
    const float* __restrict__ g2, const float* __restrict__ g3,
    const float* __restrict__ W, const float* __restrict__ b,
    float* __restrict__ out)
{
    int wid  = (blockIdx.x * 256 + threadIdx.x) >> 6;
    int lane = threadIdx.x & 63;
    if (wid >= N_NODE) return;
    size_t base = (size_t)wid * EMB + lane * 2;
    float2 v0 = *(const float2*)(e0 + base);
    float2 v1 = *(const float2*)(g1 + base);
    float2 v2 = *(const float2*)(g2 + base);
    float2 v3 = *(const float2*)(g3 + base);
    float2 w2 = *(const float2*)(W + lane * 2);
    float d0 = v0.x*w2.x + v0.y*w2.y;
    float d1 = v1.x*w2.x + v1.y*w2.y;
    float d2 = v2.x*w2.x + v2.y*w2.y;
    float d3 = v3.x*w2.x + v3.y*w2.y;
    #pragma unroll
    for (int o = 32; o > 0; o >>= 1){
        d0 += __shfl_xor(d0, o, 64); d1 += __shfl_xor(d1, o, 64);
        d2 += __shfl_xor(d2, o, 64); d3 += __shfl_xor(d3, o, 64);
    }
    float bb = b[0];
    float s0 = __expf(d0 + bb), s1 = __expf(d1 + bb);
    float s2 = __expf(d2 + bb), s3 = __expf(d3 + bb);
    float inv = 1.f / (s0 + s1 + s2 + s3);
    float2 o2;
    o2.x = (s0*v0.x + s1*v1.x + s2*v2.x + s3*v3.x) * inv;
    o2.y = (s0*v0.y + s1*v1.y + s2*v2.y + s3*v3.y) * inv;
    *(float2*)(out + base) = o2;
}

// ---------------------------------------------------------------------------
// transposed-side intra gate, phase 1. NCH=96 chunks for grid parallelism
// (cmv: 1536 blocks); bank-conflict-free FMA reads as in k_intra_v.
__global__ __launch_bounds__(256) void k_intra_tv_partial(
    const float* __restrict__ adj, const float* __restrict__ matv,
    const float* __restrict__ emb, const float* __restrict__ s_v,
    const unsigned* __restrict__ mm2,
    float* __restrict__ part, int baseR, int rows)
{
    __shared__ float sh_c[RB], sh_M[RB];
    __shared__ float sh_sv[KT2];
    __shared__ float sh_w[RB][KT2 + 1];
    __shared__ float sh_e[KT2][EMB];
    __shared__ float shZ[RB], shD[RB];
    int tid = threadIdx.x;
    int rb = blockIdx.x / NCH;
    int ch = blockIdx.x % NCH;
    int r0 = rb * RB;
    if (tid < RB){
        int r = r0 + tid;
        float c = (r < rows) ? matv[r] : 0.f;
        float smin = fdekey(mm2[0]), smax = fdekey(mm2[1]);
        sh_c[tid] = c;
        sh_M[tid] = (c >= 0.f) ? c * smax : c * smin;
        shZ[tid] = 0.f; shD[tid] = 0.f;
    }
    float zacc[8], dacc[8];
    #pragma unroll
    for (int p = 0; p < 8; p++){ zacc[p] = 0.f; dacc[p] = 0.f; }
    float acc[2][8];
    #pragma unroll
    for (int r = 0; r < 2; r++)
        #pragma unroll
        for (int d = 0; d < 8; d++) acc[r][d] = 0.f;
    int dg = tid & 15, rg = tid >> 4;
    int j0 = ch * CS;
    __syncthreads();

    for (int t = 0; t < CS / KT2; t++){
        int k0 = j0 + t * KT2;
        __syncthreads();
        if (tid < KT2) sh_sv[tid] = (k0 + tid < N_NODE) ? s_v[k0 + tid] : 0.f;
        #pragma unroll
        for (int q = 0; q < 8; q++){
            int f = tid + q * 256;
            int jl = f >> 5; int d = (f & 31) * 4;
            int j = k0 + jl;
            float4 v = (j < N_NODE) ? ((const float4*)(emb + (size_t)j*EMB + d))[0]
                                    : make_float4(0.f,0.f,0.f,0.f);
            ((float4*)&sh_e[jl][d])[0] = v;
        }
        __syncthreads();
        #pragma unroll
        for (int p = 0; p < 8; p++){
            int idx = tid + p * 256;
            int rl = idx >> 6, jl = idx & 63;
            int r = r0 + rl, j = k0 + jl;
            float w = 0.f;
            if (r < rows && j < N_NODE){
                float e = __expf(sh_c[rl] * sh_sv[jl] - sh_M[rl]);
                zacc[p] += e;
                w = e * adj[(size_t)r * N_NODE + j];
            }
            dacc[p] += w;
            sh_w[rl][jl] = w;
        }
        __syncthreads();
        #pragma unroll 4
        for (int jl = 0; jl < KT2; jl++){
            float4 e0 = ((const float4*)&sh_e[jl][dg*4])[0];
            float4 e1 = ((const float4*)&sh_e[jl][64 + dg*4])[0];
            #pragma unroll
            for (int r = 0; r < 2; r++){
                float w = sh_w[rg*2 + r][jl];
                acc[r][0] += w*e0.x; acc[r][1] += w*e0.y;
                acc[r][2] += w*e0.z; acc[r][3] += w*e0.w;
                acc[r][4] += w*e1.x; acc[r][5] += w*e1.y;
                acc[r][6] += w*e1.z; acc[r][7] += w*e1.w;
            }
        }
    }
    int a = tid >> 6;
    #pragma unroll
    for (int p = 0; p < 8; p++){
        atomicAdd(&shZ[a + 4*p], zacc[p]);
        atomicAdd(&shD[a + 4*p], dacc[p]);
    }
    __syncthreads();
    #pragma unroll
    for (int r = 0; r < 2; r++){
        int rl = rg*2 + r; int rr = r0 + rl;
        if (rr < rows){
            float* dst = part + ((size_t)(baseR + rr) * NCH + ch) * RSTRIDE;
            ((float4*)(dst + dg*4))[0]      = make_float4(acc[r][0],acc[r][1],acc[r][2],acc[r][3]);
            ((float4*)(dst + 64 + dg*4))[0] = make_float4(acc[r][4],acc[r][5],acc[r][6],acc[r][7]);
        }
    }
    if (tid < RB){
        int rr = r0 + tid;
        if (rr < rows){
            float* dst = part + ((size_t)(baseR + rr) * NCH + ch) * RSTRIDE;
            dst[128] = shD[tid]; dst[129] = shZ[tid];
        }
    }
}

// small intra gate computed fully per (row, dim) thread
__device__ inline float small_gate_col(
    const float* __restrict__ adj, const float* __restrict__ matv,
    const float* __restrict__ emb, const float* __restrict__ s,
    const unsigned* __restrict__ mm2, int K, int r, int d)
{
    float c = matv[r];
    float smin = fdekey(mm2[0]), smax = fdekey(mm2[1]);
    float M = (c >= 0.f) ? c * smax : c * smin;
    float a = 0.f, dn = 0.f, Z = 0.f;
    for (int j = 0; j < K; j++){
        float e = __expf(c * s[j] - M);
        float w = e * adj[(size_t)r * K + j];
        Z += e; dn += w;
        a += w * emb[(size_t)j * EMB + d];
    }
    return a / (dn + 1e-8f * Z);
}

// phase 2 for pri/cb/cm: reduce big-gate partials + two small gates + inter.
__global__ __launch_bounds__(128) void k_small_side(
    float* __restrict__ out, const float* __restrict__ e0,
    const float* __restrict__ part, int baseR,
    const float* __restrict__ adjA, const float* __restrict__ matA,
    const float* __restrict__ embA, const float* __restrict__ sA,
    const unsigned* __restrict__ mmA, int KA,
    const float* __restrict__ adjB, const float* __restrict__ matB,
    const float* __restrict__ embB, const float* __restrict__ sB,
    const unsigned* __restrict__ mmB, int KB,
    const float* __restrict__ W, const float* __restrict__ bptr)
{
    __shared__ float sh[4][EMB];
    __shared__ float shW[EMB];
    int r = blockIdx.x;
    int d = threadIdx.x;
    float num = 0.f, den = 0.f, Z = 0.f;
    for (int c = 0; c < NCH; c++){
        const float* p = part + ((size_t)(baseR + r) * NCH + c) * RSTRIDE;
        num += p[d]; den += p[128]; Z += p[129];
    }
    sh[1][d] = num / (den + 1e-8f * Z);
    sh[0][d] = e0[(size_t)r * EMB + d];
    shW[d] = W[d];
    sh[2][d] = small_gate_col(adjA, matA, embA, sA, mmA, KA, r, d);
    sh[3][d] = small_gate_col(adjB, matB, embB, sB, mmB, KB, r, d);
    __syncthreads();
    float dots[4];
    #pragma unroll
    for (int g = 0; g < 4; g++){
        float acc = 0.f;
        for (int k = 0; k < EMB; k++) acc += sh[g][k] * shW[k];
        dots[g] = acc;
    }
    float bb = bptr[0];
    float s0 = __expf(dots[0] + bb), s1 = __expf(dots[1] + bb);
    float s2 = __expf(dots[2] + bb), s3 = __expf(dots[3] + bb);
    float inv = 1.f / (s0 + s1 + s2 + s3);
    out[(size_t)r * EMB + d] =
        (s0*sh[0][d] + s1*sh[1][d] + s2*sh[2][d] + s3*sh[3][d]) * inv;
}

// ---------------------------------------------------------------------------
extern "C" void kernel_launch(void* const* d_in, const int* in_sizes, int n_in,
                              void* d_out, int out_size, void* d_ws, size_t ws_size,
                              hipStream_t stream)
{
    const int*   adj_idx  = (const int*)d_in[0];
    const float* adj_val  = (const float*)d_in[1];
    const float* a_pv   = (const float*)d_in[2];
    const float* a_vp   = (const float*)d_in[3];
    const float* a_pcb  = (const float*)d_in[4];
    const float* a_cbp  = (const float*)d_in[5];
    const float* a_cbv  = (const float*)d_in[6];
    const float* a_vcb  = (const float*)d_in[7];
    const float* a_pcm  = (const float*)d_in[8];
    const float* a_cmp  = (const float*)d_in[9];
    const float* a_cmv  = (const float*)d_in[10];
    const float* a_vcm  = (const float*)d_in[11];
    const float* a_cbcm = (const float*)d_in[12];
    const float* a_cmcb = (const float*)d_in[13];
    const float* in_item = (const float*)d_in[14];
    const float* in_pri  = (const float*)d_in[15];
    const float* in_cb   = (const float*)d_in[16];
    const float* in_cm   = (const float*)d_in[17];
    const float* m_vp  = (const float*)d_in[18];
    const float* m_vcb = (const float*)d_in[19];
    const float* m_vcm = (const float*)d_in[20];
    const float* m_pv  = (const float*)d_in[21];
    const float* m_pcb = (const float*)d_in[22];
    const float* m_pcm = (const float*)d_in[23];
    const float* m_cbp = (const float*)d_in[24];
    const float* m_cbv = (const float*)d_in[25];
    const float* m_cbcm= (const float*)d_in[26];
    const float* m_cmp = (const float*)d_in[27];
    const float* m_cmv = (const float*)d_in[28];
    const float* m_cmcb= (const float*)d_in[29];
    const float* Wi = (const float*)d_in[30]; const float* bi = (const float*)d_in[31];
    const float* Wp = (const float*)d_in[32]; const float* bp = (const float*)d_in[33];
    const float* Wcb= (const float*)d_in[34]; const float* bcb= (const float*)d_in[35];
    const float* Wcm= (const float*)d_in[36]; const float* bcm= (const float*)d_in[37];

    float* ws = (float*)d_ws;
    size_t off = 0;
    auto alloc = [&](size_t n){ float* p = ws + off; off += (n + 63) & ~(size_t)63; return p; };
    float* buf_item = alloc((size_t)N_NODE * EMB);
    float* buf_pri  = alloc((size_t)N_PRICE * EMB);
    float* buf_cb   = alloc((size_t)N_CB * EMB);
    float* buf_cm   = alloc((size_t)N_CM * EMB);
    float* s_all    = alloc(N_NODE + N_PRICE + N_CB + N_CM);
    unsigned* mm    = (unsigned*)alloc(64);
    float* g1 = alloc((size_t)N_NODE * EMB);
    float* g2 = alloc((size_t)N_NODE * EMB);
    float* g3 = alloc((size_t)N_NODE * EMB);
    // part: 650 rows * 96 chunks * 132 = 8.24M floats (33 MB); aliases g1+g2
    // (51.2 MB), both dead between k_inter_item and next layer's k_intra_v.
    float* part = g1;
    int*   counts = (int*)alloc(N_NODE + 64);
    int*   offs   = (int*)alloc(N_NODE + 64);
    int*   cursor = (int*)alloc(N_NODE + 64);
    int*   scol   = (int*)alloc(NNZE);
    float* sval   = alloc(NNZE);

    float* out_item = (float*)d_out;
    float* out_pri  = (float*)d_out + (size_t)N_NODE * EMB;

    const float* s_v  = s_all;
    const float* s_p  = s_all + N_NODE;
    const float* s_cb = s_all + N_NODE + N_PRICE;
    const float* s_cm = s_all + N_NODE + N_PRICE + N_CB;

    const int totr = N_NODE + N_PRICE + N_CB + N_CM;

    // ---- CSR build (once; adjacency is layer-invariant) ----
    hipMemsetAsync(counts, 0, N_NODE * sizeof(int), stream);
    k_hist<<<(NNZE + 255)/256, 256, 0, stream>>>(adj_idx, counts);
    k_scan<<<1, SCAN_T, 0, stream>>>(counts, offs, cursor);
    k_scatter<<<(NNZE + 255)/256, 256, 0, stream>>>(adj_idx, adj_idx + NNZE,
                                                    adj_val, cursor, scol, sval);

    for (int layer = 0; layer < 2; layer++){
        const float* cv  = layer ? buf_item : in_item;
        const float* cp  = layer ? buf_pri  : in_pri;
        const float* ccb = layer ? buf_cb   : in_cb;
        const float* ccm = layer ? buf_cm   : in_cm;
        float* ov = layer ? out_item : buf_item;
        float* op = layer ? out_pri  : buf_pri;

        k_rowsum<<<(totr + 3)/4, 256, 0, stream>>>(cv, cp, ccb, ccm, s_all, mm);
        k_minmax<<<(totr + 255)/256, 256, 0, stream>>>(s_all, mm);

        k_intra_v<<<(N_NODE + IB - 1)/IB, 256, 0, stream>>>(a_vp,  m_vp,  cp,  s_p,  mm+2, g1, N_PRICE);
        k_intra_v<<<(N_NODE + IB - 1)/IB, 256, 0, stream>>>(a_vcb, m_vcb, ccb, s_cb, mm+4, g2, N_CB);
        k_intra_v<<<(N_NODE + IB - 1)/IB, 256, 0, stream>>>(a_vcm, m_vcm, ccm, s_cm, mm+6, g3, N_CM);

        k_inter_item<<<(N_NODE + 3)/4, 256, 0, stream>>>(cv, g1, g2, g3, Wi, bi, ov);
        k_spmm_csr<<<(N_NODE*64 + 255)/256, 256, 0, stream>>>(offs, scol, sval, cv, ov);

        k_intra_tv_partial<<<((N_PRICE + RB - 1)/RB) * NCH, 256, 0, stream>>>(
            a_pv, m_pv, cv, s_v, mm + 0, part, 0, N_PRICE);
        if (layer == 0){
            k_intra_tv_partial<<<((N_CB + RB - 1)/RB) * NCH, 256, 0, stream>>>(
                a_cbv, m_cbv, cv, s_v, mm + 0, part, N_PRICE, N_CB);
            k_intra_tv_partial<<<((N_CM + RB - 1)/RB) * NCH, 256, 0, stream>>>(
                a_cmv, m_cmv, cv, s_v, mm + 0, part, N_PRICE + N_CB, N_CM);
        }

        k_small_side<<<N_PRICE, 128, 0, stream>>>(
            op, cp, part, 0,
            a_pcb, m_pcb, ccb, s_cb, mm+4, N_CB,
            a_pcm, m_pcm, ccm, s_cm, mm+6, N_CM,
            Wp, bp);
        if (layer == 0){
            k_small_side<<<N_CB, 128, 0, stream>>>(
                buf_cb, ccb, part, N_PRICE,
                a_cbp, m_cbp, cp, s_p, mm+2, N_PRICE,
                a_cbcm, m_cbcm, ccm, s_cm, mm+6, N_CM,
                Wcb, bcb);
            k_small_side<<<N_CM, 128, 0, stream>>>(
                buf_cm, ccm, part, N_PRICE + N_CB,
                a_cmp, m_cmp, cp, s_p, mm+2, N_PRICE,
                a_cmcb, m_cmcb, ccb, s_cb, mm+4, N_CB,
                Wcm, bcm);
        }
    }
    (void)in_sizes; (void)n_in; (void)out_size; (void)ws_size;
}

// Round 4
// 2099.938 us; speedup vs baseline: 1.9867x; 1.1358x over previous
//
#include <hip/hip_runtime.h>

#define N_NODE 50000
#define N_PRICE 100
#define N_CB 50
#define N_CM 500
#define EMB 128
#define NNZE 1000000
#define NCH 64         /* tv chunks */
#define CS2 832        /* 13 tiles of 64 cols; 64*832 = 53248 >= 50000 */
#define KVPAD 53248
#define RSTRIDE 132    /* 128 num + den + Z + pad */
#define SCAN_T 1024
#define WPAD 72        /* sh_w row stride in bf16 (64 + 8 pad) */

typedef __attribute__((ext_vector_type(8))) short bf16x8;
typedef __attribute__((ext_vector_type(4))) float f32x4;

// ---- monotone float<->uint keys for atomic min/max on floats ----
__device__ inline unsigned fkey(float f){
    unsigned b = __float_as_uint(f);
    return (b & 0x80000000u) ? ~b : (b | 0x80000000u);
}
__device__ inline float fdekey(unsigned k){
    unsigned b = (k & 0x80000000u) ? (k & 0x7fffffffu) : ~k;
    return __uint_as_float(b);
}
// fp32 -> bf16 (RNE), bit form
__device__ inline unsigned short f2bf(float f){
    unsigned u = __float_as_uint(f);
    u += 0x7FFFu + ((u >> 16) & 1u);
    return (unsigned short)(u >> 16);
}

// ---------------------------------------------------------------------------
__global__ __launch_bounds__(256) void k_rowsum(
    const float* __restrict__ e_v, const float* __restrict__ e_p,
    const float* __restrict__ e_cb, const float* __restrict__ e_cm,
    float* __restrict__ s_all, unsigned* __restrict__ mm)
{
    if (blockIdx.x == 0 && threadIdx.x < 8)
        mm[threadIdx.x] = (threadIdx.x & 1) ? 0u : 0xFFFFFFFFu;
    int wid  = (blockIdx.x * 256 + threadIdx.x) >> 6;
    int lane = threadIdx.x & 63;
    const int NT = N_NODE + N_PRICE + N_CB + N_CM;
    if (wid >= NT) return;
    const float* src; int lr;
    if (wid < N_NODE)                { src = e_v;  lr = wid; }
    else if (wid < N_NODE+N_PRICE)   { src = e_p;  lr = wid - N_NODE; }
    else if (wid < N_NODE+N_PRICE+N_CB){ src = e_cb; lr = wid - N_NODE - N_PRICE; }
    else                             { src = e_cm; lr = wid - N_NODE - N_PRICE - N_CB; }
    float2 v = ((const float2*)(src + (size_t)lr * EMB))[lane];
    float sum = v.x + v.y;
    #pragma unroll
    for (int o = 32; o > 0; o >>= 1) sum += __shfl_down(sum, o, 64);
    if (lane == 0) s_all[wid] = sum;
}

__global__ __launch_bounds__(256) void k_minmax(
    const float* __restrict__ s_all, unsigned* __restrict__ mm)
{
    __shared__ unsigned smin[4], smax[4];
    int t = threadIdx.x;
    if (t < 4){ smin[t] = 0xFFFFFFFFu; smax[t] = 0u; }
    __syncthreads();
    int gid = blockIdx.x * 256 + t;
    const int NT = N_NODE + N_PRICE + N_CB + N_CM;
    if (gid < NT){
        int ty = (gid < N_NODE) ? 0 :
                 (gid < N_NODE+N_PRICE) ? 1 :
                 (gid < N_NODE+N_PRICE+N_CB) ? 2 : 3;
        unsigned k = fkey(s_all[gid]);
        atomicMin(&smin[ty], k);
        atomicMax(&smax[ty], k);
    }
    __syncthreads();
    if (t < 4){
        if (smin[t] != 0xFFFFFFFFu) atomicMin(&mm[2*t],   smin[t]);
        if (smax[t] != 0u)          atomicMax(&mm[2*t+1], smax[t]);
    }
}

// ---------------------------------------------------------------------------
// CSR build: histogram -> scan -> scatter. Built ONCE per call, used twice.
__global__ __launch_bounds__(256) void k_hist(
    const int* __restrict__ rows, int* __restrict__ counts)
{
    int i = blockIdx.x * 256 + threadIdx.x;
    if (i < NNZE) atomicAdd(&counts[rows[i]], 1);
}

__global__ __launch_bounds__(SCAN_T) void k_scan(
    const int* __restrict__ counts, int* __restrict__ offs, int* __restrict__ cursor)
{
    __shared__ int part[SCAN_T];
    int t = threadIdx.x;
    const int CHUNK = (N_NODE + SCAN_T - 1) / SCAN_T;
    int base = t * CHUNK;
    int s = 0;
    for (int i = 0; i < CHUNK; i++){
        int idx = base + i;
        if (idx < N_NODE) s += counts[idx];
    }
    part[t] = s;
    __syncthreads();
    for (int o = 1; o < SCAN_T; o <<= 1){
        int u = (t >= o) ? part[t - o] : 0;
        __syncthreads();
        part[t] += u;
        __syncthreads();
    }
    int run = part[t] - s;
    for (int i = 0; i < CHUNK; i++){
        int idx = base + i;
        if (idx < N_NODE){
            offs[idx] = run; cursor[idx] = run;
            run += counts[idx];
        }
    }
    if (t == SCAN_T - 1) offs[N_NODE] = run;
}

__global__ __launch_bounds__(256) void k_scatter(
    const int* __restrict__ rows, const int* __restrict__ cols,
    const float* __restrict__ vals, int* __restrict__ cursor,
    int* __restrict__ scol, float* __restrict__ sval)
{
    int i = blockIdx.x * 256 + threadIdx.x;
    if (i < NNZE){
        int r = rows[i];
        int p = atomicAdd(&cursor[r], 1);
        scol[p] = cols[i];
        sval[p] = vals[i];
    }
}

// CSR spmm: one wave per row; lanes cooperatively load nnz, broadcast via shfl.
__global__ __launch_bounds__(256) void k_spmm_csr(
    const int* __restrict__ offs, const int* __restrict__ scol,
    const float* __restrict__ sval, const float* __restrict__ emb,
    float* __restrict__ out)
{
    int row  = (blockIdx.x * 256 + threadIdx.x) >> 6;
    int lane = threadIdx.x & 63;
    if (row >= N_NODE) return;
    int s = offs[row], e = offs[row + 1];
    float2 acc = make_float2(0.f, 0.f);
    for (int base = s; base < e; base += 64){
        int n = base + lane;
        int   cl = (n < e) ? scol[n] : 0;
        float vl = (n < e) ? sval[n] : 0.f;
        int m = e - base; if (m > 64) m = 64;
        for (int j = 0; j < m; j++){
            int   c = __shfl(cl, j, 64);
            float v = __shfl(vl, j, 64);
            float2 em = *(const float2*)(emb + (size_t)c * EMB + lane * 2);
            acc.x += v * em.x; acc.y += v * em.y;
        }
    }
    float* dst = out + (size_t)row * EMB + lane * 2;
    float2 o = *(float2*)dst;
    o.x += acc.x; o.y += acc.y;
    *(float2*)dst = o;
}

// ---------------------------------------------------------------------------
// Cast source embedding [K][EMB] fp32 -> transposed bf16 Et [EMB][Kpad],
// zero-padded in k. grid: (ceil(Kpad/256), EMB).
__global__ __launch_bounds__(256) void k_cast_et(
    const float* __restrict__ emb, unsigned short* __restrict__ Et,
    int K, int Kpad)
{
    int d = blockIdx.y;
    int k = blockIdx.x * 256 + threadIdx.x;
    if (k >= Kpad) return;
    float v = (k < K) ? emb[(size_t)k * EMB + d] : 0.f;
    Et[(size_t)d * Kpad + k] = f2bf(v);
}

// ---------------------------------------------------------------------------
// V-side intra gate, MFMA version. Block = 256 thr (4 waves), 64 rows, all
// 128 dims. W (exp*adj) built on the fly into LDS as bf16; E read as B-frags
// directly from global Et (L1/L2-hot). den/Z accumulated in fp32 during build.
__global__ __launch_bounds__(256) void k_intra_v_mfma(
    const float* __restrict__ adj, const float* __restrict__ matv,
    const unsigned short* __restrict__ Et, const float* __restrict__ s_src,
    const unsigned* __restrict__ mm2, float* __restrict__ out, int K, int Kpad)
{
    __shared__ unsigned short sh_w[64 * WPAD];
    __shared__ float sh_c[64], sh_M[64], shD[64], shZ[64];
    int tid = threadIdx.x;
    int i0  = blockIdx.x * 64;
    int row = tid >> 2;            // build mapping: 4 threads/row
    int j16 = (tid & 3) * 16;
    if (tid < 64){
        int i = i0 + tid;
        float c = (i < N_NODE) ? matv[i] : 0.f;
        float smin = fdekey(mm2[0]), smax = fdekey(mm2[1]);
        sh_c[tid] = c;
        sh_M[tid] = (c >= 0.f) ? c * smax : c * smin;
    }
    __syncthreads();
    float crow = sh_c[row], Mrow = sh_M[row];
    bool  rok  = (i0 + row) < N_NODE;
    const float* arow = adj + (size_t)(i0 + row) * K;
    float dpart = 0.f, zpart = 0.f;

    int wv = tid >> 6, lane = tid & 63;
    int am = lane & 15, aq = lane >> 4;
    f32x4 acc[8];
    #pragma unroll
    for (int n = 0; n < 8; n++) acc[n] = (f32x4){0.f,0.f,0.f,0.f};

    int ntile = Kpad / 64;
    for (int t = 0; t < ntile; t++){
        int k0 = t * 64;
        __syncthreads();           // sh_w consumed by previous MFMA phase
        unsigned short h[16];
        #pragma unroll
        for (int u = 0; u < 16; u++){
            int j = k0 + j16 + u;
            float w = 0.f;
            if (j < K){
                float e = __expf(crow * s_src[j] - Mrow);
                zpart += e;
                if (rok) w = e * arow[j];
            }
            dpart += w;
            h[u] = f2bf(w);
        }
        uint4* dst = (uint4*)&sh_w[row * WPAD + j16];
        dst[0] = make_uint4(((unsigned)h[1]<<16)|h[0], ((unsigned)h[3]<<16)|h[2],
                            ((unsigned)h[5]<<16)|h[4], ((unsigned)h[7]<<16)|h[6]);
        dst[1] = make_uint4(((unsigned)h[9]<<16)|h[8], ((unsigned)h[11]<<16)|h[10],
                            ((unsigned)h[13]<<16)|h[12],((unsigned)h[15]<<16)|h[14]);
        __syncthreads();
        #pragma unroll
        for (int ks = 0; ks < 2; ks++){
            bf16x8 afrag = *(const bf16x8*)&sh_w[(wv*16 + am) * WPAD + ks*32 + aq*8];
            #pragma unroll
            for (int n = 0; n < 8; n++){
                bf16x8 bfrag = *(const bf16x8*)&Et[(size_t)(n*16 + am) * Kpad + k0 + ks*32 + aq*8];
                acc[n] = __builtin_amdgcn_mfma_f32_16x16x32_bf16(afrag, bfrag, acc[n], 0, 0, 0);
            }
        }
    }
    // reduce den/Z over the 4 build-threads of each row (same wave: lanes xor 1,2)
    dpart += __shfl_xor(dpart, 1, 64); dpart += __shfl_xor(dpart, 2, 64);
    zpart += __shfl_xor(zpart, 1, 64); zpart += __shfl_xor(zpart, 2, 64);
    if ((tid & 3) == 0){ shD[row] = dpart; shZ[row] = zpart; }
    __syncthreads();
    #pragma unroll
    for (int n = 0; n < 8; n++){
        #pragma unroll
        for (int r = 0; r < 4; r++){
            int rl = wv*16 + aq*4 + r;
            int i  = i0 + rl;
            if (i < N_NODE){
                float inv = 1.f / (shD[rl] + 1e-8f * shZ[rl]);
                out[(size_t)i * EMB + n*16 + am] = acc[n][r] * inv;
            }
        }
    }
}

// ---------------------------------------------------------------------------
// transposed-side intra gate (MFMA), phase 1: 64 rows/block, chunk of CS2
// item-cols, writes partial (num[128], den, Z) per (row, chunk).
__global__ __launch_bounds__(256) void k_intra_tv_mfma(
    const float* __restrict__ adj, const float* __restrict__ matv,
    const unsigned short* __restrict__ Et, const float* __restrict__ s_v,
    const unsigned* __restrict__ mm2,
    float* __restrict__ part, int baseR, int rows)
{
    __shared__ unsigned short sh_w[64 * WPAD];
    __shared__ float sh_c[64], sh_M[64];
    int tid = threadIdx.x;
    int rb = blockIdx.x / NCH;
    int ch = blockIdx.x % NCH;
    int r0 = rb * 64;
    int row = tid >> 2;
    int j16 = (tid & 3) * 16;
    if (tid < 64){
        int r = r0 + tid;
        float c = (r < rows) ? matv[r] : 0.f;
        float smin = fdekey(mm2[0]), smax = fdekey(mm2[1]);
        sh_c[tid] = c;
        sh_M[tid] = (c >= 0.f) ? c * smax : c * smin;
    }
    __syncthreads();
    float crow = sh_c[row], Mrow = sh_M[row];
    bool  rok  = (r0 + row) < rows;
    const float* arow = adj + (size_t)(r0 + row) * N_NODE;
    float dpart = 0.f, zpart = 0.f;

    int wv = tid >> 6, lane = tid & 63;
    int am = lane & 15, aq = lane >> 4;
    f32x4 acc[8];
    #pragma unroll
    for (int n = 0; n < 8; n++) acc[n] = (f32x4){0.f,0.f,0.f,0.f};

    for (int t = 0; t < CS2 / 64; t++){
        int k0 = ch * CS2 + t * 64;
        __syncthreads();
        unsigned short h[16];
        #pragma unroll
        for (int u = 0; u < 16; u++){
            int j = k0 + j16 + u;
            float w = 0.f;
            if (j < N_NODE){
                float e = __expf(crow * s_v[j] - Mrow);
                zpart += e;
                if (rok) w = e * arow[j];
            }
            dpart += w;
            h[u] = f2bf(w);
        }
        uint4* dst = (uint4*)&sh_w[row * WPAD + j16];
        dst[0] = make_uint4(((unsigned)h[1]<<16)|h[0], ((unsigned)h[3]<<16)|h[2],
                            ((unsigned)h[5]<<16)|h[4], ((unsigned)h[7]<<16)|h[6]);
        dst[1] = make_uint4(((unsigned)h[9]<<16)|h[8], ((unsigned)h[11]<<16)|h[10],
                            ((unsigned)h[13]<<16)|h[12],((unsigned)h[15]<<16)|h[14]);
        __syncthreads();
        #pragma unroll
        for (int ks = 0; ks < 2; ks++){
            bf16x8 afrag = *(const bf16x8*)&sh_w[(wv*16 + am) * WPAD + ks*32 + aq*8];
            #pragma unroll
            for (int n = 0; n < 8; n++){
                bf16x8 bfrag = *(const bf16x8*)&Et[(size_t)(n*16 + am) * KVPAD + k0 + ks*32 + aq*8];
                acc[n] = __builtin_amdgcn_mfma_f32_16x16x32_bf16(afrag, bfrag, acc[n], 0, 0, 0);
            }
        }
    }
    dpart += __shfl_xor(dpart, 1, 64); dpart += __shfl_xor(dpart, 2, 64);
    zpart += __shfl_xor(zpart, 1, 64); zpart += __shfl_xor(zpart, 2, 64);
    if ((tid & 3) == 0 && rok){
        float* d2 = part + ((size_t)(baseR + r0 + row) * NCH + ch) * RSTRIDE;
        d2[128] = dpart; d2[129] = zpart;
    }
    #pragma unroll
    for (int n = 0; n < 8; n++){
        #pragma unroll
        for (int r = 0; r < 4; r++){
            int rl = wv*16 + aq*4 + r;
            int rr = r0 + rl;
            if (rr < rows){
                float* d2 = part + ((size_t)(baseR + rr) * NCH + ch) * RSTRIDE;
                d2[n*16 + am] = acc[n][r];
            }
        }
    }
}

// ---------------------------------------------------------------------------
__global__ __launch_bounds__(256) void k_inter_item(
    const float* __restrict__ e0, const float* __restrict__ g1,
    const float* __restrict__ g2, const float* __restrict__ g3,
    const float* __restrict__ W, const float* __restrict__ b,
    float* __restrict__ out)
{
    int wid  = (blockIdx.x * 256 + threadIdx.x) >> 6;
    int lane = threadIdx.x & 63;
    if (wid >= N_NODE) return;
    size_t base = (size_t)wid * EMB + lane * 2;
    float2 v0 = *(const float2*)(e0 + base);
    float2 v1 = *(const float2*)(g1 + base);
    float2 v2 = *(const float2*)(g2 + base);
    float2 v3 = *(const float2*)(g3 + base);
    float2 w2 = *(const float2*)(W + lane * 2);
    float d0 = v0.x*w2.x + v0.y*w2.y;
    float d1 = v1.x*w2.x + v1.y*w2.y;
    float d2 = v2.x*w2.x + v2.y*w2.y;
    float d3 = v3.x*w2.x + v3.y*w2.y;
    #pragma unroll
    for (int o = 32; o > 0; o >>= 1){
        d0 += __shfl_xor(d0, o, 64); d1 += __shfl_xor(d1, o, 64);
        d2 += __shfl_xor(d2, o, 64); d3 += __shfl_xor(d3, o, 64);
    }
    float bb = b[0];
    float s0 = __expf(d0 + bb), s1 = __expf(d1 + bb);
    float s2 = __expf(d2 + bb), s3 = __expf(d3 + bb);
    float inv = 1.f / (s0 + s1 + s2 + s3);
    float2 o2;
    o2.x = (s0*v0.x + s1*v1.x + s2*v2.x + s3*v3.x) * inv;
    o2.y = (s0*v0.y + s1*v1.y + s2*v2.y + s3*v3.y) * inv;
    *(float2*)(out + base) = o2;
}

// small intra gate computed fully per (row, dim) thread
__device__ inline float small_gate_col(
    const float* __restrict__ adj, const float* __restrict__ matv,
    const float* __restrict__ emb, const float* __restrict__ s,
    const unsigned* __restrict__ mm2, int K, int r, int d)
{
    float c = matv[r];
    float smin = fdekey(mm2[0]), smax = fdekey(mm2[1]);
    float M = (c >= 0.f) ? c * smax : c * smin;
    float a = 0.f, dn = 0.f, Z = 0.f;
    for (int j = 0; j < K; j++){
        float e = __expf(c * s[j] - M);
        float w = e * adj[(size_t)r * K + j];
        Z += e; dn += w;
        a += w * emb[(size_t)j * EMB + d];
    }
    return a / (dn + 1e-8f * Z);
}

// phase 2 for pri/cb/cm: reduce big-gate partials + two small gates + inter.
__global__ __launch_bounds__(128) void k_small_side(
    float* __restrict__ out, const float* __restrict__ e0,
    const float* __restrict__ part, int baseR,
    const float* __restrict__ adjA, const float* __restrict__ matA,
    const float* __restrict__ embA, const float* __restrict__ sA,
    const unsigned* __restrict__ mmA, int KA,
    const float* __restrict__ adjB, const float* __restrict__ matB,
    const float* __restrict__ embB, const float* __restrict__ sB,
    const unsigned* __restrict__ mmB, int KB,
    const float* __restrict__ W, const float* __restrict__ bptr)
{
    __shared__ float sh[4][EMB];
    __shared__ float shW[EMB];
    int r = blockIdx.x;
    int d = threadIdx.x;
    float num = 0.f, den = 0.f, Z = 0.f;
    for (int c = 0; c < NCH; c++){
        const float* p = part + ((size_t)(baseR + r) * NCH + c) * RSTRIDE;
        num += p[d]; den += p[128]; Z += p[129];
    }
    sh[1][d] = num / (den + 1e-8f * Z);
    sh[0][d] = e0[(size_t)r * EMB + d];
    shW[d] = W[d];
    sh[2][d] = small_gate_col(adjA, matA, embA, sA, mmA, KA, r, d);
    sh[3][d] = small_gate_col(adjB, matB, embB, sB, mmB, KB, r, d);
    __syncthreads();
    float dots[4];
    #pragma unroll
    for (int g = 0; g < 4; g++){
        float acc = 0.f;
        for (int k = 0; k < EMB; k++) acc += sh[g][k] * shW[k];
        dots[g] = acc;
    }
    float bb = bptr[0];
    float s0 = __expf(dots[0] + bb), s1 = __expf(dots[1] + bb);
    float s2 = __expf(dots[2] + bb), s3 = __expf(dots[3] + bb);
    float inv = 1.f / (s0 + s1 + s2 + s3);
    out[(size_t)r * EMB + d] =
        (s0*sh[0][d] + s1*sh[1][d] + s2*sh[2][d] + s3*sh[3][d]) * inv;
}

// ---------------------------------------------------------------------------
extern "C" void kernel_launch(void* const* d_in, const int* in_sizes, int n_in,
                              void* d_out, int out_size, void* d_ws, size_t ws_size,
                              hipStream_t stream)
{
    const int*   adj_idx  = (const int*)d_in[0];
    const float* adj_val  = (const float*)d_in[1];
    const float* a_pv   = (const float*)d_in[2];
    const float* a_vp   = (const float*)d_in[3];
    const float* a_pcb  = (const float*)d_in[4];
    const float* a_cbp  = (const float*)d_in[5];
    const float* a_cbv  = (const float*)d_in[6];
    const float* a_vcb  = (const float*)d_in[7];
    const float* a_pcm  = (const float*)d_in[8];
    const float* a_cmp  = (const float*)d_in[9];
    const float* a_cmv  = (const float*)d_in[10];
    const float* a_vcm  = (const float*)d_in[11];
    const float* a_cbcm = (const float*)d_in[12];
    const float* a_cmcb = (const float*)d_in[13];
    const float* in_item = (const float*)d_in[14];
    const float* in_pri  = (const float*)d_in[15];
    const float* in_cb   = (const float*)d_in[16];
    const float* in_cm   = (const float*)d_in[17];
    const float* m_vp  = (const float*)d_in[18];
    const float* m_vcb = (const float*)d_in[19];
    const float* m_vcm = (const float*)d_in[20];
    const float* m_pv  = (const float*)d_in[21];
    const float* m_pcb = (const float*)d_in[22];
    const float* m_pcm = (const float*)d_in[23];
    const float* m_cbp = (const float*)d_in[24];
    const float* m_cbv = (const float*)d_in[25];
    const float* m_cbcm= (const float*)d_in[26];
    const float* m_cmp = (const float*)d_in[27];
    const float* m_cmv = (const float*)d_in[28];
    const float* m_cmcb= (const float*)d_in[29];
    const float* Wi = (const float*)d_in[30]; const float* bi = (const float*)d_in[31];
    const float* Wp = (const float*)d_in[32]; const float* bp = (const float*)d_in[33];
    const float* Wcb= (const float*)d_in[34]; const float* bcb= (const float*)d_in[35];
    const float* Wcm= (const float*)d_in[36]; const float* bcm= (const float*)d_in[37];

    float* ws = (float*)d_ws;
    size_t off = 0;
    auto alloc = [&](size_t n){ float* p = ws + off; off += (n + 63) & ~(size_t)63; return p; };
    float* buf_item = alloc((size_t)N_NODE * EMB);
    float* buf_pri  = alloc((size_t)N_PRICE * EMB);
    float* buf_cb   = alloc((size_t)N_CB * EMB);
    float* buf_cm   = alloc((size_t)N_CM * EMB);
    float* s_all    = alloc(N_NODE + N_PRICE + N_CB + N_CM);
    unsigned* mm    = (unsigned*)alloc(64);
    float* g1 = alloc((size_t)N_NODE * EMB);
    float* g2 = alloc((size_t)N_NODE * EMB);
    float* g3 = alloc((size_t)N_NODE * EMB);
    // part: 650 rows * 64 chunks * 132 = 5.49M floats (22 MB); aliases g1
    // (25.6 MB), dead between k_inter_item and next layer's k_intra_v.
    float* part = g1;
    // et_v (bf16 [128][KVPAD] = 13.6 MB) aliases g3 (25.6 MB); g3 dead after
    // k_inter_item; rebuilt each layer before tv kernels.
    unsigned short* et_v = (unsigned short*)g3;
    int*   counts = (int*)alloc(N_NODE + 64);
    int*   offs   = (int*)alloc(N_NODE + 64);
    int*   cursor = (int*)alloc(N_NODE + 64);
    int*   scol   = (int*)alloc(NNZE);
    float* sval   = alloc(NNZE);
    unsigned short* et_p  = (unsigned short*)alloc(EMB * 128 / 2);
    unsigned short* et_cb = (unsigned short*)alloc(EMB * 64 / 2);
    unsigned short* et_cm = (unsigned short*)alloc(EMB * 512 / 2);

    float* out_item = (float*)d_out;
    float* out_pri  = (float*)d_out + (size_t)N_NODE * EMB;

    const float* s_v  = s_all;
    const float* s_p  = s_all + N_NODE;
    const float* s_cb = s_all + N_NODE + N_PRICE;
    const float* s_cm = s_all + N_NODE + N_PRICE + N_CB;

    const int totr = N_NODE + N_PRICE + N_CB + N_CM;

    // ---- CSR build (once; adjacency is layer-invariant) ----
    hipMemsetAsync(counts, 0, N_NODE * sizeof(int), stream);
    k_hist<<<(NNZE + 255)/256, 256, 0, stream>>>(adj_idx, counts);
    k_scan<<<1, SCAN_T, 0, stream>>>(counts, offs, cursor);
    k_scatter<<<(NNZE + 255)/256, 256, 0, stream>>>(adj_idx, adj_idx + NNZE,
                                                    adj_val, cursor, scol, sval);

    for (int layer = 0; layer < 2; layer++){
        const float* cv  = layer ? buf_item : in_item;
        const float* cp  = layer ? buf_pri  : in_pri;
        const float* ccb = layer ? buf_cb   : in_cb;
        const float* ccm = layer ? buf_cm   : in_cm;
        float* ov = layer ? out_item : buf_item;
        float* op = layer ? out_pri  : buf_pri;

        k_rowsum<<<(totr + 3)/4, 256, 0, stream>>>(cv, cp, ccb, ccm, s_all, mm);
        k_minmax<<<(totr + 255)/256, 256, 0, stream>>>(s_all, mm);

        // bf16 transposed operands for the V-side gates
        k_cast_et<<<dim3(1, EMB), 256, 0, stream>>>(cp,  et_p,  N_PRICE, 128);
        k_cast_et<<<dim3(1, EMB), 256, 0, stream>>>(ccb, et_cb, N_CB,    64);
        k_cast_et<<<dim3(2, EMB), 256, 0, stream>>>(ccm, et_cm, N_CM,    512);

        k_intra_v_mfma<<<(N_NODE + 63)/64, 256, 0, stream>>>(a_vp,  m_vp,  et_p,  s_p,  mm+2, g1, N_PRICE, 128);
        k_intra_v_mfma<<<(N_NODE + 63)/64, 256, 0, stream>>>(a_vcb, m_vcb, et_cb, s_cb, mm+4, g2, N_CB,    64);
        k_intra_v_mfma<<<(N_NODE + 63)/64, 256, 0, stream>>>(a_vcm, m_vcm, et_cm, s_cm, mm+6, g3, N_CM,    512);

        k_inter_item<<<(N_NODE + 3)/4, 256, 0, stream>>>(cv, g1, g2, g3, Wi, bi, ov);
        k_spmm_csr<<<(N_NODE*64 + 255)/256, 256, 0, stream>>>(offs, scol, sval, cv, ov);

        // item-side bf16 transposed operand (aliases g3, now dead)
        k_cast_et<<<dim3((KVPAD + 255)/256, EMB), 256, 0, stream>>>(cv, et_v, N_NODE, KVPAD);

        k_intra_tv_mfma<<<((N_PRICE + 63)/64) * NCH, 256, 0, stream>>>(
            a_pv, m_pv, et_v, s_v, mm + 0, part, 0, N_PRICE);
        if (layer == 0){
            k_intra_tv_mfma<<<((N_CB + 63)/64) * NCH, 256, 0, stream>>>(
                a_cbv, m_cbv, et_v, s_v, mm + 0, part, N_PRICE, N_CB);
            k_intra_tv_mfma<<<((N_CM + 63)/64) * NCH, 256, 0, stream>>>(
                a_cmv, m_cmv, et_v, s_v, mm + 0, part, N_PRICE + N_CB, N_CM);
        }

        k_small_side<<<N_PRICE, 128, 0, stream>>>(
            op, cp, part, 0,
            a_pcb, m_pcb, ccb, s_cb, mm+4, N_CB,
            a_pcm, m_pcm, ccm, s_cm, mm+6, N_CM,
            Wp, bp);
        if (layer == 0){
            k_small_side<<<N_CB, 128, 0, stream>>>(
                buf_cb, ccb, part, N_PRICE,
                a_cbp, m_cbp, cp, s_p, mm+2, N_PRICE,
                a_cbcm, m_cbcm, ccm, s_cm, mm+6, N_CM,
                Wcb, bcb);
            k_small_side<<<N_CM, 128, 0, stream>>>(
                buf_cm, ccm, part, N_PRICE + N_CB,
                a_cmp, m_cmp, cp, s_p, mm+2, N_PRICE,
                a_cmcb, m_cmcb, ccb, s_cb, mm+4, N_CB,
                Wcm, bcm);
        }
    }
    (void)in_sizes; (void)n_in; (void)out_size; (void)ws_size;
}

// Round 5
// 1922.582 us; speedup vs baseline: 2.1699x; 1.0922x over previous
//
#include <hip/hip_runtime.h>

#define N_NODE 50000
#define N_PRICE 100
#define N_CB 50
#define N_CM 500
#define EMB 128
#define NNZE 1000000
#define NCH 64         /* tv chunks */
#define CS2 832        /* 13 tiles of 64 cols; 64*832 = 53248 >= 50000 */
#define KVPAD 53248
#define RSTRIDE 132    /* 128 num + den + Z + pad */
#define SCAN_T 1024
#define WPAD 72        /* sh_w row stride in bf16 (64 + 8 pad) */

typedef __attribute__((ext_vector_type(8))) short bf16x8;
typedef __attribute__((ext_vector_type(4))) float f32x4;

// ---- monotone float<->uint keys for atomic min/max on floats ----
__device__ inline unsigned fkey(float f){
    unsigned b = __float_as_uint(f);
    return (b & 0x80000000u) ? ~b : (b | 0x80000000u);
}
__device__ inline float fdekey(unsigned k){
    unsigned b = (k & 0x80000000u) ? (k & 0x7fffffffu) : ~k;
    return __uint_as_float(b);
}
// fp32 -> bf16 (RNE), bit form
__device__ inline unsigned short f2bf(float f){
    unsigned u = __float_as_uint(f);
    u += 0x7FFFu + ((u >> 16) & 1u);
    return (unsigned short)(u >> 16);
}

// ---------------------------------------------------------------------------
__global__ __launch_bounds__(256) void k_rowsum(
    const float* __restrict__ e_v, const float* __restrict__ e_p,
    const float* __restrict__ e_cb, const float* __restrict__ e_cm,
    float* __restrict__ s_all, unsigned* __restrict__ mm)
{
    if (blockIdx.x == 0 && threadIdx.x < 8)
        mm[threadIdx.x] = (threadIdx.x & 1) ? 0u : 0xFFFFFFFFu;
    int wid  = (blockIdx.x * 256 + threadIdx.x) >> 6;
    int lane = threadIdx.x & 63;
    const int NT = N_NODE + N_PRICE + N_CB + N_CM;
    if (wid >= NT) return;
    const float* src; int lr;
    if (wid < N_NODE)                { src = e_v;  lr = wid; }
    else if (wid < N_NODE+N_PRICE)   { src = e_p;  lr = wid - N_NODE; }
    else if (wid < N_NODE+N_PRICE+N_CB){ src = e_cb; lr = wid - N_NODE - N_PRICE; }
    else                             { src = e_cm; lr = wid - N_NODE - N_PRICE - N_CB; }
    float2 v = ((const float2*)(src + (size_t)lr * EMB))[lane];
    float sum = v.x + v.y;
    #pragma unroll
    for (int o = 32; o > 0; o >>= 1) sum += __shfl_down(sum, o, 64);
    if (lane == 0) s_all[wid] = sum;
}

__global__ __launch_bounds__(256) void k_minmax(
    const float* __restrict__ s_all, unsigned* __restrict__ mm)
{
    __shared__ unsigned smin[4], smax[4];
    int t = threadIdx.x;
    if (t < 4){ smin[t] = 0xFFFFFFFFu; smax[t] = 0u; }
    __syncthreads();
    int gid = blockIdx.x * 256 + t;
    const int NT = N_NODE + N_PRICE + N_CB + N_CM;
    if (gid < NT){
        int ty = (gid < N_NODE) ? 0 :
                 (gid < N_NODE+N_PRICE) ? 1 :
                 (gid < N_NODE+N_PRICE+N_CB) ? 2 : 3;
        unsigned k = fkey(s_all[gid]);
        atomicMin(&smin[ty], k);
        atomicMax(&smax[ty], k);
    }
    __syncthreads();
    if (t < 4){
        if (smin[t] != 0xFFFFFFFFu) atomicMin(&mm[2*t],   smin[t]);
        if (smax[t] != 0u)          atomicMax(&mm[2*t+1], smax[t]);
    }
}

// ---------------------------------------------------------------------------
// CSR build: histogram -> scan -> scatter. Built ONCE per call, used twice.
__global__ __launch_bounds__(256) void k_hist(
    const int* __restrict__ rows, int* __restrict__ counts)
{
    int i = blockIdx.x * 256 + threadIdx.x;
    if (i < NNZE) atomicAdd(&counts[rows[i]], 1);
}

__global__ __launch_bounds__(SCAN_T) void k_scan(
    const int* __restrict__ counts, int* __restrict__ offs, int* __restrict__ cursor)
{
    __shared__ int part[SCAN_T];
    int t = threadIdx.x;
    const int CHUNK = (N_NODE + SCAN_T - 1) / SCAN_T;
    int base = t * CHUNK;
    int s = 0;
    for (int i = 0; i < CHUNK; i++){
        int idx = base + i;
        if (idx < N_NODE) s += counts[idx];
    }
    part[t] = s;
    __syncthreads();
    for (int o = 1; o < SCAN_T; o <<= 1){
        int u = (t >= o) ? part[t - o] : 0;
        __syncthreads();
        part[t] += u;
        __syncthreads();
    }
    int run = part[t] - s;
    for (int i = 0; i < CHUNK; i++){
        int idx = base + i;
        if (idx < N_NODE){
            offs[idx] = run; cursor[idx] = run;
            run += counts[idx];
        }
    }
    if (t == SCAN_T - 1) offs[N_NODE] = run;
}

__global__ __launch_bounds__(256) void k_scatter(
    const int* __restrict__ rows, const int* __restrict__ cols,
    const float* __restrict__ vals, int* __restrict__ cursor,
    int* __restrict__ scol, float* __restrict__ sval)
{
    int i = blockIdx.x * 256 + threadIdx.x;
    if (i < NNZE){
        int r = rows[i];
        int p = atomicAdd(&cursor[r], 1);
        scol[p] = cols[i];
        sval[p] = vals[i];
    }
}

// CSR spmm: one wave per row; lanes cooperatively load nnz, broadcast via shfl.
__global__ __launch_bounds__(256) void k_spmm_csr(
    const int* __restrict__ offs, const int* __restrict__ scol,
    const float* __restrict__ sval, const float* __restrict__ emb,
    float* __restrict__ out)
{
    int row  = (blockIdx.x * 256 + threadIdx.x) >> 6;
    int lane = threadIdx.x & 63;
    if (row >= N_NODE) return;
    int s = offs[row], e = offs[row + 1];
    float2 acc = make_float2(0.f, 0.f);
    for (int base = s; base < e; base += 64){
        int n = base + lane;
        int   cl = (n < e) ? scol[n] : 0;
        float vl = (n < e) ? sval[n] : 0.f;
        int m = e - base; if (m > 64) m = 64;
        for (int j = 0; j < m; j++){
            int   c = __shfl(cl, j, 64);
            float v = __shfl(vl, j, 64);
            float2 em = *(const float2*)(emb + (size_t)c * EMB + lane * 2);
            acc.x += v * em.x; acc.y += v * em.y;
        }
    }
    float* dst = out + (size_t)row * EMB + lane * 2;
    float2 o = *(float2*)dst;
    o.x += acc.x; o.y += acc.y;
    *(float2*)dst = o;
}

// ---------------------------------------------------------------------------
// Cast source embedding [K][EMB] fp32 -> transposed bf16 Et [EMB][Kpad].
__global__ __launch_bounds__(256) void k_cast_et(
    const float* __restrict__ emb, unsigned short* __restrict__ Et,
    int K, int Kpad)
{
    int d = blockIdx.y;
    int k = blockIdx.x * 256 + threadIdx.x;
    if (k >= Kpad) return;
    float v = (k < K) ? emb[(size_t)k * EMB + d] : 0.f;
    Et[(size_t)d * Kpad + k] = f2bf(v);
}

// ---------------------------------------------------------------------------
// Shared MFMA gate block body: 64 rows x all 128 dims of
// out[i,:] = (sum_j w_ij E[j,:]) / (den_i + 1e-8 Z_i), w = exp(c_i s_j - M_i)*adj.
// If writeDiv: divide and store to out[i*EMB+d]; else store raw num to out and
// den/Z to auxiliary slots (not used here; V-side always divides).
__device__ inline void gate_block_mfma(
    const float* __restrict__ adj, const float* __restrict__ matv,
    const unsigned short* __restrict__ Et, const float* __restrict__ s_src,
    const unsigned* __restrict__ mm2, float* __restrict__ out,
    int K, int Kpad, int nrows, int i0,
    unsigned short* sh_w, float* sh_c, float* sh_M, float* shD, float* shZ)
{
    int tid = threadIdx.x;
    int row = tid >> 2;
    int j16 = (tid & 3) * 16;
    if (tid < 64){
        int i = i0 + tid;
        float c = (i < nrows) ? matv[i] : 0.f;
        float smin = fdekey(mm2[0]), smax = fdekey(mm2[1]);
        sh_c[tid] = c;
        sh_M[tid] = (c >= 0.f) ? c * smax : c * smin;
    }
    __syncthreads();
    float crow = sh_c[row], Mrow = sh_M[row];
    bool  rok  = (i0 + row) < nrows;
    const float* arow = adj + (size_t)(rok ? (i0 + row) : 0) * K;
    float dpart = 0.f, zpart = 0.f;

    int wv = tid >> 6, lane = tid & 63;
    int am = lane & 15, aq = lane >> 4;
    f32x4 acc[8];
    #pragma unroll
    for (int n = 0; n < 8; n++) acc[n] = (f32x4){0.f,0.f,0.f,0.f};

    int ntile = Kpad / 64;
    for (int t = 0; t < ntile; t++){
        int k0 = t * 64;
        __syncthreads();
        unsigned short h[16];
        #pragma unroll
        for (int u = 0; u < 16; u++){
            int j = k0 + j16 + u;
            float w = 0.f;
            if (j < K){
                float e = __expf(crow * s_src[j] - Mrow);
                zpart += e;
                if (rok) w = e * arow[j];
            }
            dpart += w;
            h[u] = f2bf(w);
        }
        uint4* dst = (uint4*)&sh_w[row * WPAD + j16];
        dst[0] = make_uint4(((unsigned)h[1]<<16)|h[0], ((unsigned)h[3]<<16)|h[2],
                            ((unsigned)h[5]<<16)|h[4], ((unsigned)h[7]<<16)|h[6]);
        dst[1] = make_uint4(((unsigned)h[9]<<16)|h[8], ((unsigned)h[11]<<16)|h[10],
                            ((unsigned)h[13]<<16)|h[12],((unsigned)h[15]<<16)|h[14]);
        __syncthreads();
        #pragma unroll
        for (int ks = 0; ks < 2; ks++){
            bf16x8 afrag = *(const bf16x8*)&sh_w[(wv*16 + am) * WPAD + ks*32 + aq*8];
            #pragma unroll
            for (int n = 0; n < 8; n++){
                bf16x8 bfrag = *(const bf16x8*)&Et[(size_t)(n*16 + am) * Kpad + k0 + ks*32 + aq*8];
                acc[n] = __builtin_amdgcn_mfma_f32_16x16x32_bf16(afrag, bfrag, acc[n], 0, 0, 0);
            }
        }
    }
    dpart += __shfl_xor(dpart, 1, 64); dpart += __shfl_xor(dpart, 2, 64);
    zpart += __shfl_xor(zpart, 1, 64); zpart += __shfl_xor(zpart, 2, 64);
    if ((tid & 3) == 0){ shD[row] = dpart; shZ[row] = zpart; }
    __syncthreads();
    #pragma unroll
    for (int n = 0; n < 8; n++){
        #pragma unroll
        for (int r = 0; r < 4; r++){
            int rl = wv*16 + aq*4 + r;
            int i  = i0 + rl;
            if (i < nrows){
                float inv = 1.f / (shD[rl] + 1e-8f * shZ[rl]);
                out[(size_t)i * EMB + n*16 + am] = acc[n][r] * inv;
            }
        }
    }
}

// V-side intra gate (50000 rows).
__global__ __launch_bounds__(256) void k_intra_v_mfma(
    const float* __restrict__ adj, const float* __restrict__ matv,
    const unsigned short* __restrict__ Et, const float* __restrict__ s_src,
    const unsigned* __restrict__ mm2, float* __restrict__ out, int K, int Kpad)
{
    __shared__ unsigned short sh_w[64 * WPAD];
    __shared__ float sh_c[64], sh_M[64], shD[64], shZ[64];
    gate_block_mfma(adj, matv, Et, s_src, mm2, out, K, Kpad, N_NODE,
                    blockIdx.x * 64, sh_w, sh_c, sh_M, shD, shZ);
}

// Batched small gates: one launch, 6 jobs max.
struct GateJob {
    const float* adj; const float* matv; const unsigned short* Et;
    const float* s; const unsigned* mm2; float* out;
    int K, Kpad, nrows, blk0;
};
struct GateJobs { GateJob j[6]; int njobs; };

__global__ __launch_bounds__(256) void k_gate_batch(GateJobs jobs)
{
    __shared__ unsigned short sh_w[64 * WPAD];
    __shared__ float sh_c[64], sh_M[64], shD[64], shZ[64];
    int b = blockIdx.x;
    int ji = 0;
    for (int q = 1; q < jobs.njobs; q++) if (b >= jobs.j[q].blk0) ji = q;
    GateJob J = jobs.j[ji];
    gate_block_mfma(J.adj, J.matv, J.Et, J.s, J.mm2, J.out, J.K, J.Kpad,
                    J.nrows, (b - J.blk0) * 64, sh_w, sh_c, sh_M, shD, shZ);
}

// ---------------------------------------------------------------------------
// transposed-side intra gate (MFMA), phase 1: 64 rows/block, chunk of CS2
// item-cols, writes partial (num[128], den, Z) per (row, chunk).
__global__ __launch_bounds__(256) void k_intra_tv_mfma(
    const float* __restrict__ adj, const float* __restrict__ matv,
    const unsigned short* __restrict__ Et, const float* __restrict__ s_v,
    const unsigned* __restrict__ mm2,
    float* __restrict__ part, int baseR, int rows)
{
    __shared__ unsigned short sh_w[64 * WPAD];
    __shared__ float sh_c[64], sh_M[64];
    int tid = threadIdx.x;
    int rb = blockIdx.x / NCH;
    int ch = blockIdx.x % NCH;
    int r0 = rb * 64;
    int row = tid >> 2;
    int j16 = (tid & 3) * 16;
    if (tid < 64){
        int r = r0 + tid;
        float c = (r < rows) ? matv[r] : 0.f;
        float smin = fdekey(mm2[0]), smax = fdekey(mm2[1]);
        sh_c[tid] = c;
        sh_M[tid] = (c >= 0.f) ? c * smax : c * smin;
    }
    __syncthreads();
    float crow = sh_c[row], Mrow = sh_M[row];
    bool  rok  = (r0 + row) < rows;
    const float* arow = adj + (size_t)(rok ? (r0 + row) : 0) * N_NODE;
    float dpart = 0.f, zpart = 0.f;

    int wv = tid >> 6, lane = tid & 63;
    int am = lane & 15, aq = lane >> 4;
    f32x4 acc[8];
    #pragma unroll
    for (int n = 0; n < 8; n++) acc[n] = (f32x4){0.f,0.f,0.f,0.f};

    for (int t = 0; t < CS2 / 64; t++){
        int k0 = ch * CS2 + t * 64;
        __syncthreads();
        unsigned short h[16];
        #pragma unroll
        for (int u = 0; u < 16; u++){
            int j = k0 + j16 + u;
            float w = 0.f;
            if (j < N_NODE){
                float e = __expf(crow * s_v[j] - Mrow);
                zpart += e;
                if (rok) w = e * arow[j];
            }
            dpart += w;
            h[u] = f2bf(w);
        }
        uint4* dst = (uint4*)&sh_w[row * WPAD + j16];
        dst[0] = make_uint4(((unsigned)h[1]<<16)|h[0], ((unsigned)h[3]<<16)|h[2],
                            ((unsigned)h[5]<<16)|h[4], ((unsigned)h[7]<<16)|h[6]);
        dst[1] = make_uint4(((unsigned)h[9]<<16)|h[8], ((unsigned)h[11]<<16)|h[10],
                            ((unsigned)h[13]<<16)|h[12],((unsigned)h[15]<<16)|h[14]);
        __syncthreads();
        #pragma unroll
        for (int ks = 0; ks < 2; ks++){
            bf16x8 afrag = *(const bf16x8*)&sh_w[(wv*16 + am) * WPAD + ks*32 + aq*8];
            #pragma unroll
            for (int n = 0; n < 8; n++){
                bf16x8 bfrag = *(const bf16x8*)&Et[(size_t)(n*16 + am) * KVPAD + k0 + ks*32 + aq*8];
                acc[n] = __builtin_amdgcn_mfma_f32_16x16x32_bf16(afrag, bfrag, acc[n], 0, 0, 0);
            }
        }
    }
    dpart += __shfl_xor(dpart, 1, 64); dpart += __shfl_xor(dpart, 2, 64);
    zpart += __shfl_xor(zpart, 1, 64); zpart += __shfl_xor(zpart, 2, 64);
    if ((tid & 3) == 0 && rok){
        float* d2 = part + ((size_t)(baseR + r0 + row) * NCH + ch) * RSTRIDE;
        d2[128] = dpart; d2[129] = zpart;
    }
    #pragma unroll
    for (int n = 0; n < 8; n++){
        #pragma unroll
        for (int r = 0; r < 4; r++){
            int rl = wv*16 + aq*4 + r;
            int rr = r0 + rl;
            if (rr < rows){
                float* d2 = part + ((size_t)(baseR + rr) * NCH + ch) * RSTRIDE;
                d2[n*16 + am] = acc[n][r];
            }
        }
    }
}

// ---------------------------------------------------------------------------
__global__ __launch_bounds__(256) void k_inter_item(
    const float* __restrict__ e0, const float* __restrict__ g1,
    const float* __restrict__ g2, const float* __restrict__ g3,
    const float* __restrict__ W, const float* __restrict__ b,
    float* __restrict__ out)
{
    int wid  = (blockIdx.x * 256 + threadIdx.x) >> 6;
    int lane = threadIdx.x & 63;
    if (wid >= N_NODE) return;
    size_t base = (size_t)wid * EMB + lane * 2;
    float2 v0 = *(const float2*)(e0 + base);
    float2 v1 = *(const float2*)(g1 + base);
    float2 v2 = *(const float2*)(g2 + base);
    float2 v3 = *(const float2*)(g3 + base);
    float2 w2 = *(const float2*)(W + lane * 2);
    float d0 = v0.x*w2.x + v0.y*w2.y;
    float d1 = v1.x*w2.x + v1.y*w2.y;
    float d2 = v2.x*w2.x + v2.y*w2.y;
    float d3 = v3.x*w2.x + v3.y*w2.y;
    #pragma unroll
    for (int o = 32; o > 0; o >>= 1){
        d0 += __shfl_xor(d0, o, 64); d1 += __shfl_xor(d1, o, 64);
        d2 += __shfl_xor(d2, o, 64); d3 += __shfl_xor(d3, o, 64);
    }
    float bb = b[0];
    float s0 = __expf(d0 + bb), s1 = __expf(d1 + bb);
    float s2 = __expf(d2 + bb), s3 = __expf(d3 + bb);
    float inv = 1.f / (s0 + s1 + s2 + s3);
    float2 o2;
    o2.x = (s0*v0.x + s1*v1.x + s2*v2.x + s3*v3.x) * inv;
    o2.y = (s0*v0.y + s1*v1.y + s2*v2.y + s3*v3.y) * inv;
    *(float2*)(out + base) = o2;
}

// ---------------------------------------------------------------------------
// Batched phase-2: reduce big-gate partials over NCH chunks + 4-way inter
// gate from precomputed small-gate buffers. One 128-thr block per row.
struct RIJob {
    const float* e0; float* out; const float* gA; const float* gB;
    const float* W; const float* b; int baseR; int nrows; int row0;
};
struct RIJobs { RIJob j[3]; int njobs; };

__global__ __launch_bounds__(128) void k_reduce_inter(
    RIJobs jobs, const float* __restrict__ part)
{
    __shared__ float sh[4][EMB];
    __shared__ float shW[EMB];
    int b = blockIdx.x;
    int ji = 0;
    for (int q = 1; q < jobs.njobs; q++) if (b >= jobs.j[q].row0) ji = q;
    RIJob J = jobs.j[ji];
    int r = b - J.row0;
    int d = threadIdx.x;
    float num = 0.f, den = 0.f, Z = 0.f;
    for (int c = 0; c < NCH; c++){
        const float* p = part + ((size_t)(J.baseR + r) * NCH + c) * RSTRIDE;
        num += p[d]; den += p[128]; Z += p[129];
    }
    sh[1][d] = num / (den + 1e-8f * Z);
    sh[0][d] = J.e0[(size_t)r * EMB + d];
    sh[2][d] = J.gA[(size_t)r * EMB + d];
    sh[3][d] = J.gB[(size_t)r * EMB + d];
    shW[d] = J.W[d];
    __syncthreads();
    float dots[4];
    #pragma unroll
    for (int g = 0; g < 4; g++){
        float acc = 0.f;
        for (int k = 0; k < EMB; k++) acc += sh[g][k] * shW[k];
        dots[g] = acc;
    }
    float bb = J.b[0];
    float s0 = __expf(dots[0] + bb), s1 = __expf(dots[1] + bb);
    float s2 = __expf(dots[2] + bb), s3 = __expf(dots[3] + bb);
    float inv = 1.f / (s0 + s1 + s2 + s3);
    J.out[(size_t)r * EMB + d] =
        (s0*sh[0][d] + s1*sh[1][d] + s2*sh[2][d] + s3*sh[3][d]) * inv;
}

// ---------------------------------------------------------------------------
extern "C" void kernel_launch(void* const* d_in, const int* in_sizes, int n_in,
                              void* d_out, int out_size, void* d_ws, size_t ws_size,
                              hipStream_t stream)
{
    const int*   adj_idx  = (const int*)d_in[0];
    const float* adj_val  = (const float*)d_in[1];
    const float* a_pv   = (const float*)d_in[2];
    const float* a_vp   = (const float*)d_in[3];
    const float* a_pcb  = (const float*)d_in[4];
    const float* a_cbp  = (const float*)d_in[5];
    const float* a_cbv  = (const float*)d_in[6];
    const float* a_vcb  = (const float*)d_in[7];
    const float* a_pcm  = (const float*)d_in[8];
    const float* a_cmp  = (const float*)d_in[9];
    const float* a_cmv  = (const float*)d_in[10];
    const float* a_vcm  = (const float*)d_in[11];
    const float* a_cbcm = (const float*)d_in[12];
    const float* a_cmcb = (const float*)d_in[13];
    const float* in_item = (const float*)d_in[14];
    const float* in_pri  = (const float*)d_in[15];
    const float* in_cb   = (const float*)d_in[16];
    const float* in_cm   = (const float*)d_in[17];
    const float* m_vp  = (const float*)d_in[18];
    const float* m_vcb = (const float*)d_in[19];
    const float* m_vcm = (const float*)d_in[20];
    const float* m_pv  = (const float*)d_in[21];
    const float* m_pcb = (const float*)d_in[22];
    const float* m_pcm = (const float*)d_in[23];
    const float* m_cbp = (const float*)d_in[24];
    const float* m_cbv = (const float*)d_in[25];
    const float* m_cbcm= (const float*)d_in[26];
    const float* m_cmp = (const float*)d_in[27];
    const float* m_cmv = (const float*)d_in[28];
    const float* m_cmcb= (const float*)d_in[29];
    const float* Wi = (const float*)d_in[30]; const float* bi = (const float*)d_in[31];
    const float* Wp = (const float*)d_in[32]; const float* bp = (const float*)d_in[33];
    const float* Wcb= (const float*)d_in[34]; const float* bcb= (const float*)d_in[35];
    const float* Wcm= (const float*)d_in[36]; const float* bcm= (const float*)d_in[37];

    float* ws = (float*)d_ws;
    size_t off = 0;
    auto alloc = [&](size_t n){ float* p = ws + off; off += (n + 63) & ~(size_t)63; return p; };
    float* buf_item = alloc((size_t)N_NODE * EMB);
    float* buf_pri  = alloc((size_t)N_PRICE * EMB);
    float* buf_cb   = alloc((size_t)N_CB * EMB);
    float* buf_cm   = alloc((size_t)N_CM * EMB);
    float* s_all    = alloc(N_NODE + N_PRICE + N_CB + N_CM);
    unsigned* mm    = (unsigned*)alloc(64);
    float* g1 = alloc((size_t)N_NODE * EMB);
    float* g2 = alloc((size_t)N_NODE * EMB);
    float* g3 = alloc((size_t)N_NODE * EMB);
    float* part = g1;                       // 650*64*132 = 5.49M floats, alias g1
    unsigned short* et_v = (unsigned short*)g3;  // 13.6 MB, alias g3
    int*   counts = (int*)alloc(N_NODE + 64);
    int*   offs   = (int*)alloc(N_NODE + 64);
    int*   cursor = (int*)alloc(N_NODE + 64);
    int*   scol   = (int*)alloc(NNZE);
    float* sval   = alloc(NNZE);
    unsigned short* et_p  = (unsigned short*)alloc(EMB * 128 / 2);
    unsigned short* et_cb = (unsigned short*)alloc(EMB * 64 / 2);
    unsigned short* et_cm = (unsigned short*)alloc(EMB * 512 / 2);
    float* g_pcb  = alloc((size_t)N_PRICE * EMB);
    float* g_pcm  = alloc((size_t)N_PRICE * EMB);
    float* g_cbp  = alloc((size_t)N_CB * EMB);
    float* g_cbcm = alloc((size_t)N_CB * EMB);
    float* g_cmp  = alloc((size_t)N_CM * EMB);
    float* g_cmcb = alloc((size_t)N_CM * EMB);

    float* out_item = (float*)d_out;
    float* out_pri  = (float*)d_out + (size_t)N_NODE * EMB;

    const float* s_v  = s_all;
    const float* s_p  = s_all + N_NODE;
    const float* s_cb = s_all + N_NODE + N_PRICE;
    const float* s_cm = s_all + N_NODE + N_PRICE + N_CB;

    const int totr = N_NODE + N_PRICE + N_CB + N_CM;

    // ---- CSR build (once; adjacency is layer-invariant) ----
    hipMemsetAsync(counts, 0, N_NODE * sizeof(int), stream);
    k_hist<<<(NNZE + 255)/256, 256, 0, stream>>>(adj_idx, counts);
    k_scan<<<1, SCAN_T, 0, stream>>>(counts, offs, cursor);
    k_scatter<<<(NNZE + 255)/256, 256, 0, stream>>>(adj_idx, adj_idx + NNZE,
                                                    adj_val, cursor, scol, sval);

    for (int layer = 0; layer < 2; layer++){
        const float* cv  = layer ? buf_item : in_item;
        const float* cp  = layer ? buf_pri  : in_pri;
        const float* ccb = layer ? buf_cb   : in_cb;
        const float* ccm = layer ? buf_cm   : in_cm;
        float* ov = layer ? out_item : buf_item;
        float* op = layer ? out_pri  : buf_pri;

        k_rowsum<<<(totr + 3)/4, 256, 0, stream>>>(cv, cp, ccb, ccm, s_all, mm);
        k_minmax<<<(totr + 255)/256, 256, 0, stream>>>(s_all, mm);

        // bf16 transposed operands for p/cb/cm-source gates
        k_cast_et<<<dim3(1, EMB), 256, 0, stream>>>(cp,  et_p,  N_PRICE, 128);
        k_cast_et<<<dim3(1, EMB), 256, 0, stream>>>(ccb, et_cb, N_CB,    64);
        k_cast_et<<<dim3(2, EMB), 256, 0, stream>>>(ccm, et_cm, N_CM,    512);

        // batched small gates (MFMA)
        GateJobs gj{};
        int nb = 0, nj = 0;
        auto addjob = [&](const float* adj_, const float* matv_,
                          const unsigned short* Et_, const float* s_,
                          const unsigned* mm2_, float* out_,
                          int K_, int Kpad_, int nrows_){
            gj.j[nj] = GateJob{adj_, matv_, Et_, s_, mm2_, out_,
                               K_, Kpad_, nrows_, nb};
            nb += (nrows_ + 63) / 64; nj++;
        };
        addjob(a_pcb, m_pcb, et_cb, s_cb, mm+4, g_pcb, N_CB,    64, N_PRICE);
        addjob(a_pcm, m_pcm, et_cm, s_cm, mm+6, g_pcm, N_CM,   512, N_PRICE);
        if (layer == 0){
            addjob(a_cbp,  m_cbp,  et_p,  s_p,  mm+2, g_cbp,  N_PRICE, 128, N_CB);
            addjob(a_cbcm, m_cbcm, et_cm, s_cm, mm+6, g_cbcm, N_CM,   512, N_CB);
            addjob(a_cmp,  m_cmp,  et_p,  s_p,  mm+2, g_cmp,  N_PRICE, 128, N_CM);
            addjob(a_cmcb, m_cmcb, et_cb, s_cb, mm+4, g_cmcb, N_CB,    64, N_CM);
        }
        gj.njobs = nj;
        k_gate_batch<<<nb, 256, 0, stream>>>(gj);

        k_intra_v_mfma<<<(N_NODE + 63)/64, 256, 0, stream>>>(a_vp,  m_vp,  et_p,  s_p,  mm+2, g1, N_PRICE, 128);
        k_intra_v_mfma<<<(N_NODE + 63)/64, 256, 0, stream>>>(a_vcb, m_vcb, et_cb, s_cb, mm+4, g2, N_CB,    64);
        k_intra_v_mfma<<<(N_NODE + 63)/64, 256, 0, stream>>>(a_vcm, m_vcm, et_cm, s_cm, mm+6, g3, N_CM,    512);

        k_inter_item<<<(N_NODE + 3)/4, 256, 0, stream>>>(cv, g1, g2, g3, Wi, bi, ov);
        k_spmm_csr<<<(N_NODE*64 + 255)/256, 256, 0, stream>>>(offs, scol, sval, cv, ov);

        // item-side bf16 transposed operand (aliases g3, now dead)
        k_cast_et<<<dim3((KVPAD + 255)/256, EMB), 256, 0, stream>>>(cv, et_v, N_NODE, KVPAD);

        k_intra_tv_mfma<<<((N_PRICE + 63)/64) * NCH, 256, 0, stream>>>(
            a_pv, m_pv, et_v, s_v, mm + 0, part, 0, N_PRICE);
        if (layer == 0){
            k_intra_tv_mfma<<<((N_CB + 63)/64) * NCH, 256, 0, stream>>>(
                a_cbv, m_cbv, et_v, s_v, mm + 0, part, N_PRICE, N_CB);
            k_intra_tv_mfma<<<((N_CM + 63)/64) * NCH, 256, 0, stream>>>(
                a_cmv, m_cmv, et_v, s_v, mm + 0, part, N_PRICE + N_CB, N_CM);
        }

        // batched phase-2 reduce + inter
        RIJobs rj{};
        rj.j[0] = RIJob{cp, op, g_pcb, g_pcm, Wp, bp, 0, N_PRICE, 0};
        int nrows_tot = N_PRICE;
        int njr = 1;
        if (layer == 0){
            rj.j[1] = RIJob{ccb, buf_cb, g_cbp, g_cbcm, Wcb, bcb,
                            N_PRICE, N_CB, nrows_tot};
            nrows_tot += N_CB; njr++;
            rj.j[2] = RIJob{ccm, buf_cm, g_cmp, g_cmcb, Wcm, bcm,
                            N_PRICE + N_CB, N_CM, nrows_tot};
            nrows_tot += N_CM; njr++;
        }
        rj.njobs = njr;
        k_reduce_inter<<<nrows_tot, 128, 0, stream>>>(rj, part);
    }
    (void)in_sizes; (void)n_in; (void)out_size; (void)ws_size;
}

// Round 6
// 1659.006 us; speedup vs baseline: 2.5147x; 1.1589x over previous
//
#include <hip/hip_runtime.h>

#define N_NODE 50000
#define N_PRICE 100
#define N_CB 50
#define N_CM 500
#define EMB 128
#define NNZE 1000000
#define NCH 64         /* tv chunks */
#define CS2 832        /* 13 tiles of 64 cols; 64*832 = 53248 >= 50000 */
#define KVPAD 53248
#define RSTRIDE 132    /* 128 num + den + Z + pad */
#define SCAN_T 1024
#define WPAD 72        /* sh_w row stride in bf16 (64 + 8 pad) */
#define E0P 132        /* sh_e0 row stride (fp32), 16B-aligned rows */

typedef __attribute__((ext_vector_type(8))) short bf16x8;
typedef __attribute__((ext_vector_type(4))) float f32x4;

// ---- monotone float<->uint keys for atomic min/max on floats ----
__device__ inline unsigned fkey(float f){
    unsigned b = __float_as_uint(f);
    return (b & 0x80000000u) ? ~b : (b | 0x80000000u);
}
__device__ inline float fdekey(unsigned k){
    unsigned b = (k & 0x80000000u) ? (k & 0x7fffffffu) : ~k;
    return __uint_as_float(b);
}
// fp32 -> bf16 (RNE), bit form
__device__ inline unsigned short f2bf(float f){
    unsigned u = __float_as_uint(f);
    u += 0x7FFFu + ((u >> 16) & 1u);
    return (unsigned short)(u >> 16);
}

// ---------------------------------------------------------------------------
__global__ __launch_bounds__(256) void k_rowsum(
    const float* __restrict__ e_v, const float* __restrict__ e_p,
    const float* __restrict__ e_cb, const float* __restrict__ e_cm,
    float* __restrict__ s_all, unsigned* __restrict__ mm)
{
    if (blockIdx.x == 0 && threadIdx.x < 8)
        mm[threadIdx.x] = (threadIdx.x & 1) ? 0u : 0xFFFFFFFFu;
    int wid  = (blockIdx.x * 256 + threadIdx.x) >> 6;
    int lane = threadIdx.x & 63;
    const int NT = N_NODE + N_PRICE + N_CB + N_CM;
    if (wid >= NT) return;
    const float* src; int lr;
    if (wid < N_NODE)                { src = e_v;  lr = wid; }
    else if (wid < N_NODE+N_PRICE)   { src = e_p;  lr = wid - N_NODE; }
    else if (wid < N_NODE+N_PRICE+N_CB){ src = e_cb; lr = wid - N_NODE - N_PRICE; }
    else                             { src = e_cm; lr = wid - N_NODE - N_PRICE - N_CB; }
    float2 v = ((const float2*)(src + (size_t)lr * EMB))[lane];
    float sum = v.x + v.y;
    #pragma unroll
    for (int o = 32; o > 0; o >>= 1) sum += __shfl_down(sum, o, 64);
    if (lane == 0) s_all[wid] = sum;
}

__global__ __launch_bounds__(256) void k_minmax(
    const float* __restrict__ s_all, unsigned* __restrict__ mm)
{
    __shared__ unsigned smin[4], smax[4];
    int t = threadIdx.x;
    if (t < 4){ smin[t] = 0xFFFFFFFFu; smax[t] = 0u; }
    __syncthreads();
    int gid = blockIdx.x * 256 + t;
    const int NT = N_NODE + N_PRICE + N_CB + N_CM;
    if (gid < NT){
        int ty = (gid < N_NODE) ? 0 :
                 (gid < N_NODE+N_PRICE) ? 1 :
                 (gid < N_NODE+N_PRICE+N_CB) ? 2 : 3;
        unsigned k = fkey(s_all[gid]);
        atomicMin(&smin[ty], k);
        atomicMax(&smax[ty], k);
    }
    __syncthreads();
    if (t < 4){
        if (smin[t] != 0xFFFFFFFFu) atomicMin(&mm[2*t],   smin[t]);
        if (smax[t] != 0u)          atomicMax(&mm[2*t+1], smax[t]);
    }
}

// ---------------------------------------------------------------------------
// CSR build: histogram -> scan -> scatter. Built ONCE per call, used twice.
__global__ __launch_bounds__(256) void k_hist(
    const int* __restrict__ rows, int* __restrict__ counts)
{
    int i = blockIdx.x * 256 + threadIdx.x;
    if (i < NNZE) atomicAdd(&counts[rows[i]], 1);
}

__global__ __launch_bounds__(SCAN_T) void k_scan(
    const int* __restrict__ counts, int* __restrict__ offs, int* __restrict__ cursor)
{
    __shared__ int part[SCAN_T];
    int t = threadIdx.x;
    const int CHUNK = (N_NODE + SCAN_T - 1) / SCAN_T;
    int base = t * CHUNK;
    int s = 0;
    for (int i = 0; i < CHUNK; i++){
        int idx = base + i;
        if (idx < N_NODE) s += counts[idx];
    }
    part[t] = s;
    __syncthreads();
    for (int o = 1; o < SCAN_T; o <<= 1){
        int u = (t >= o) ? part[t - o] : 0;
        __syncthreads();
        part[t] += u;
        __syncthreads();
    }
    int run = part[t] - s;
    for (int i = 0; i < CHUNK; i++){
        int idx = base + i;
        if (idx < N_NODE){
            offs[idx] = run; cursor[idx] = run;
            run += counts[idx];
        }
    }
    if (t == SCAN_T - 1) offs[N_NODE] = run;
}

__global__ __launch_bounds__(256) void k_scatter(
    const int* __restrict__ rows, const int* __restrict__ cols,
    const float* __restrict__ vals, int* __restrict__ cursor,
    int* __restrict__ scol, float* __restrict__ sval)
{
    int i = blockIdx.x * 256 + threadIdx.x;
    if (i < NNZE){
        int r = rows[i];
        int p = atomicAdd(&cursor[r], 1);
        scol[p] = cols[i];
        sval[p] = vals[i];
    }
}

// CSR spmm: one wave per row; lanes cooperatively load nnz, broadcast via shfl.
__global__ __launch_bounds__(256) void k_spmm_csr(
    const int* __restrict__ offs, const int* __restrict__ scol,
    const float* __restrict__ sval, const float* __restrict__ emb,
    float* __restrict__ out)
{
    int row  = (blockIdx.x * 256 + threadIdx.x) >> 6;
    int lane = threadIdx.x & 63;
    if (row >= N_NODE) return;
    int s = offs[row], e = offs[row + 1];
    float2 acc = make_float2(0.f, 0.f);
    for (int base = s; base < e; base += 64){
        int n = base + lane;
        int   cl = (n < e) ? scol[n] : 0;
        float vl = (n < e) ? sval[n] : 0.f;
        int m = e - base; if (m > 64) m = 64;
        for (int j = 0; j < m; j++){
            int   c = __shfl(cl, j, 64);
            float v = __shfl(vl, j, 64);
            float2 em = *(const float2*)(emb + (size_t)c * EMB + lane * 2);
            acc.x += v * em.x; acc.y += v * em.y;
        }
    }
    float* dst = out + (size_t)row * EMB + lane * 2;
    float2 o = *(float2*)dst;
    o.x += acc.x; o.y += acc.y;
    *(float2*)dst = o;
}

// ---------------------------------------------------------------------------
// Cast source embedding [K][EMB] fp32 -> transposed bf16 Et [EMB][Kpad].
__global__ __launch_bounds__(256) void k_cast_et(
    const float* __restrict__ emb, unsigned short* __restrict__ Et,
    int K, int Kpad)
{
    int d = blockIdx.y;
    int k = blockIdx.x * 256 + threadIdx.x;
    if (k >= Kpad) return;
    float v = (k < K) ? emb[(size_t)k * EMB + d] : 0.f;
    Et[(size_t)d * Kpad + k] = f2bf(v);
}

// ---------------------------------------------------------------------------
// Shared MFMA gate block body (used by the batched small-gate kernel).
__device__ inline void gate_block_mfma(
    const float* __restrict__ adj, const float* __restrict__ matv,
    const unsigned short* __restrict__ Et, const float* __restrict__ s_src,
    const unsigned* __restrict__ mm2, float* __restrict__ out,
    int K, int Kpad, int nrows, int i0,
    unsigned short* sh_w, float* sh_c, float* sh_M, float* shD, float* shZ)
{
    int tid = threadIdx.x;
    int row = tid >> 2;
    int j16 = (tid & 3) * 16;
    if (tid < 64){
        int i = i0 + tid;
        float c = (i < nrows) ? matv[i] : 0.f;
        float smin = fdekey(mm2[0]), smax = fdekey(mm2[1]);
        sh_c[tid] = c;
        sh_M[tid] = (c >= 0.f) ? c * smax : c * smin;
    }
    __syncthreads();
    float crow = sh_c[row], Mrow = sh_M[row];
    bool  rok  = (i0 + row) < nrows;
    const float* arow = adj + (size_t)(rok ? (i0 + row) : 0) * K;
    float dpart = 0.f, zpart = 0.f;

    int wv = tid >> 6, lane = tid & 63;
    int am = lane & 15, aq = lane >> 4;
    f32x4 acc[8];
    #pragma unroll
    for (int n = 0; n < 8; n++) acc[n] = (f32x4){0.f,0.f,0.f,0.f};

    int ntile = Kpad / 64;
    for (int t = 0; t < ntile; t++){
        int k0 = t * 64;
        __syncthreads();
        unsigned short h[16];
        #pragma unroll
        for (int u = 0; u < 16; u++){
            int j = k0 + j16 + u;
            float w = 0.f;
            if (j < K){
                float e = __expf(crow * s_src[j] - Mrow);
                zpart += e;
                if (rok) w = e * arow[j];
            }
            dpart += w;
            h[u] = f2bf(w);
        }
        uint4* dst = (uint4*)&sh_w[row * WPAD + j16];
        dst[0] = make_uint4(((unsigned)h[1]<<16)|h[0], ((unsigned)h[3]<<16)|h[2],
                            ((unsigned)h[5]<<16)|h[4], ((unsigned)h[7]<<16)|h[6]);
        dst[1] = make_uint4(((unsigned)h[9]<<16)|h[8], ((unsigned)h[11]<<16)|h[10],
                            ((unsigned)h[13]<<16)|h[12],((unsigned)h[15]<<16)|h[14]);
        __syncthreads();
        #pragma unroll
        for (int ks = 0; ks < 2; ks++){
            bf16x8 afrag = *(const bf16x8*)&sh_w[(wv*16 + am) * WPAD + ks*32 + aq*8];
            #pragma unroll
            for (int n = 0; n < 8; n++){
                bf16x8 bfrag = *(const bf16x8*)&Et[(size_t)(n*16 + am) * Kpad + k0 + ks*32 + aq*8];
                acc[n] = __builtin_amdgcn_mfma_f32_16x16x32_bf16(afrag, bfrag, acc[n], 0, 0, 0);
            }
        }
    }
    dpart += __shfl_xor(dpart, 1, 64); dpart += __shfl_xor(dpart, 2, 64);
    zpart += __shfl_xor(zpart, 1, 64); zpart += __shfl_xor(zpart, 2, 64);
    if ((tid & 3) == 0){ shD[row] = dpart; shZ[row] = zpart; }
    __syncthreads();
    #pragma unroll
    for (int n = 0; n < 8; n++){
        #pragma unroll
        for (int r = 0; r < 4; r++){
            int rl = wv*16 + aq*4 + r;
            int i  = i0 + rl;
            if (i < nrows){
                float inv = 1.f / (shD[rl] + 1e-8f * shZ[rl]);
                out[(size_t)i * EMB + n*16 + am] = acc[n][r] * inv;
            }
        }
    }
}

// Batched small gates: one launch, 6 jobs max.
struct GateJob {
    const float* adj; const float* matv; const unsigned short* Et;
    const float* s; const unsigned* mm2; float* out;
    int K, Kpad, nrows, blk0;
};
struct GateJobs { GateJob j[6]; int njobs; };

__global__ __launch_bounds__(256) void k_gate_batch(GateJobs jobs)
{
    __shared__ unsigned short sh_w[64 * WPAD];
    __shared__ float sh_c[64], sh_M[64], shD[64], shZ[64];
    int b = blockIdx.x;
    int ji = 0;
    for (int q = 1; q < jobs.njobs; q++) if (b >= jobs.j[q].blk0) ji = q;
    GateJob J = jobs.j[ji];
    gate_block_mfma(J.adj, J.matv, J.Et, J.s, J.mm2, J.out, J.K, J.Kpad,
                    J.nrows, (b - J.blk0) * 64, sh_w, sh_c, sh_M, shD, shZ);
}

// ---------------------------------------------------------------------------
// FUSED item update: three V-side intra gates (MFMA, adj-prefetched) + the
// 4-way inter gate, all per 64-row block. out = inter(e0, g_vp, g_vcb, g_vcm).
struct FGate {
    const float* adj; const float* matv; const unsigned short* Et;
    const unsigned* mm2; int K, Kpad, soff;
};
struct FParams { FGate g[3]; };

__global__ __launch_bounds__(256) void k_item_fused(
    FParams P, const float* __restrict__ cv, const float* __restrict__ sseg,
    const float* __restrict__ W, const float* __restrict__ bptr,
    float* __restrict__ out)
{
    __shared__ unsigned short sh_w[64 * WPAD];
    __shared__ float sh_e0[64 * E0P];
    __shared__ float shs[656];
    __shared__ float sh_c[3][64], sh_M[3][64];
    __shared__ float shD[64], shZ[64];
    __shared__ float shWf[128];

    int tid = threadIdx.x;
    int i0  = blockIdx.x * 64;

    for (int j = tid; j < 650; j += 256) shs[j] = sseg[j];
    if (tid < 128) shWf[tid] = W[tid];
    if (tid < 192){
        int g = tid >> 6, r = tid & 63;
        int i = i0 + r;
        float c = (i < N_NODE) ? P.g[g].matv[i] : 0.f;
        float smin = fdekey(P.g[g].mm2[0]), smax = fdekey(P.g[g].mm2[1]);
        sh_c[g][r] = c;
        sh_M[g][r] = (c >= 0.f) ? c * smax : c * smin;
    }
    for (int f = tid; f < 64 * 32; f += 256){
        int row = f >> 5, d4 = (f & 31) * 4;
        int i = i0 + row;
        float4 v = (i < N_NODE) ? ((const float4*)(cv + (size_t)i * EMB + d4))[0]
                                : make_float4(0.f,0.f,0.f,0.f);
        ((float4*)&sh_e0[row * E0P + d4])[0] = v;
    }
    __syncthreads();

    int row = tid >> 2, j16 = (tid & 3) * 16;
    int wv = tid >> 6, lane = tid & 63, am = lane & 15, aq = lane >> 4;
    int ir = i0 + row; if (ir > N_NODE - 1) ir = N_NODE - 1;
    bool rok = (i0 + row) < N_NODE;
    float bb = bptr[0];

    // e0 inter-term: dot with W (butterfly over am lanes), seed run-acc.
    float dp[4] = {0.f,0.f,0.f,0.f};
    #pragma unroll
    for (int n = 0; n < 8; n++)
        #pragma unroll
        for (int r = 0; r < 4; r++)
            dp[r] += sh_e0[(wv*16 + aq*4 + r) * E0P + n*16 + am] * shWf[n*16 + am];
    #pragma unroll
    for (int o = 1; o <= 8; o <<= 1)
        #pragma unroll
        for (int r = 0; r < 4; r++) dp[r] += __shfl_xor(dp[r], o, 64);
    float stot[4];
    #pragma unroll
    for (int r = 0; r < 4; r++) stot[r] = __expf(dp[r] + bb);
    f32x4 run[8];
    #pragma unroll
    for (int n = 0; n < 8; n++)
        #pragma unroll
        for (int r = 0; r < 4; r++)
            run[n][r] = stot[r] * sh_e0[(wv*16 + aq*4 + r) * E0P + n*16 + am];

    for (int g = 0; g < 3; g++){
        FGate G = P.g[g];
        float crow = sh_c[g][row], Mrow = sh_M[g][row];
        const float* arow = G.adj + (size_t)ir * G.K;
        const float* srcs = shs + G.soff;
        f32x4 acc[8];
        #pragma unroll
        for (int n = 0; n < 8; n++) acc[n] = (f32x4){0.f,0.f,0.f,0.f};
        float dpart = 0.f, zpart = 0.f;
        int ntile = G.Kpad >> 6;

        float apref[16];
        #pragma unroll
        for (int u = 0; u < 16; u++){
            int j = j16 + u;
            apref[u] = (rok && j < G.K) ? arow[j] : 0.f;
        }
        for (int t = 0; t < ntile; t++){
            int k0 = t * 64;
            unsigned short h[16];
            #pragma unroll
            for (int u = 0; u < 16; u++){
                int j = k0 + j16 + u;
                float w = 0.f;
                if (j < G.K){
                    float e = __expf(crow * srcs[j] - Mrow);
                    zpart += e;
                    w = e * apref[u];
                }
                dpart += w;
                h[u] = f2bf(w);
            }
            __syncthreads();   // previous MFMA done reading sh_w
            uint4* dst = (uint4*)&sh_w[row * WPAD + j16];
            dst[0] = make_uint4(((unsigned)h[1]<<16)|h[0], ((unsigned)h[3]<<16)|h[2],
                                ((unsigned)h[5]<<16)|h[4], ((unsigned)h[7]<<16)|h[6]);
            dst[1] = make_uint4(((unsigned)h[9]<<16)|h[8], ((unsigned)h[11]<<16)|h[10],
                                ((unsigned)h[13]<<16)|h[12],((unsigned)h[15]<<16)|h[14]);
            __syncthreads();   // sh_w visible
            if (t + 1 < ntile){
                int k0n = (t + 1) * 64;
                #pragma unroll
                for (int u = 0; u < 16; u++){
                    int j = k0n + j16 + u;
                    apref[u] = (rok && j < G.K) ? arow[j] : 0.f;
                }
            }
            #pragma unroll
            for (int ks = 0; ks < 2; ks++){
                bf16x8 afrag = *(const bf16x8*)&sh_w[(wv*16 + am) * WPAD + ks*32 + aq*8];
                #pragma unroll
                for (int n = 0; n < 8; n++){
                    bf16x8 bfrag = *(const bf16x8*)&G.Et[(size_t)(n*16 + am) * G.Kpad + k0 + ks*32 + aq*8];
                    acc[n] = __builtin_amdgcn_mfma_f32_16x16x32_bf16(afrag, bfrag, acc[n], 0, 0, 0);
                }
            }
        }
        dpart += __shfl_xor(dpart, 1, 64); dpart += __shfl_xor(dpart, 2, 64);
        zpart += __shfl_xor(zpart, 1, 64); zpart += __shfl_xor(zpart, 2, 64);
        if ((tid & 3) == 0){ shD[row] = dpart; shZ[row] = zpart; }
        __syncthreads();
        float inv[4];
        #pragma unroll
        for (int r = 0; r < 4; r++){
            int rl = wv*16 + aq*4 + r;
            inv[r] = 1.f / (shD[rl] + 1e-8f * shZ[rl]);
        }
        float dpg[4] = {0.f,0.f,0.f,0.f};
        #pragma unroll
        for (int n = 0; n < 8; n++)
            #pragma unroll
            for (int r = 0; r < 4; r++){
                acc[n][r] *= inv[r];
                dpg[r] += acc[n][r] * shWf[n*16 + am];
            }
        #pragma unroll
        for (int o = 1; o <= 8; o <<= 1)
            #pragma unroll
            for (int r = 0; r < 4; r++) dpg[r] += __shfl_xor(dpg[r], o, 64);
        #pragma unroll
        for (int r = 0; r < 4; r++){
            float sg = __expf(dpg[r] + bb);
            stot[r] += sg;
            #pragma unroll
            for (int n = 0; n < 8; n++) run[n][r] += sg * acc[n][r];
        }
    }
    float invs[4];
    #pragma unroll
    for (int r = 0; r < 4; r++) invs[r] = 1.f / stot[r];
    #pragma unroll
    for (int n = 0; n < 8; n++)
        #pragma unroll
        for (int r = 0; r < 4; r++){
            int i = i0 + wv*16 + aq*4 + r;
            if (i < N_NODE) out[(size_t)i * EMB + n*16 + am] = run[n][r] * invs[r];
        }
}

// ---------------------------------------------------------------------------
// transposed-side intra gate (MFMA), phase 1: 64 rows/block, chunk of CS2
// item-cols, writes partial (num[128], den, Z) per (row, chunk).
__global__ __launch_bounds__(256) void k_intra_tv_mfma(
    const float* __restrict__ adj, const float* __restrict__ matv,
    const unsigned short* __restrict__ Et, const float* __restrict__ s_v,
    const unsigned* __restrict__ mm2,
    float* __restrict__ part, int baseR, int rows)
{
    __shared__ unsigned short sh_w[64 * WPAD];
    __shared__ float sh_c[64], sh_M[64];
    int tid = threadIdx.x;
    int rb = blockIdx.x / NCH;
    int ch = blockIdx.x % NCH;
    int r0 = rb * 64;
    int row = tid >> 2;
    int j16 = (tid & 3) * 16;
    if (tid < 64){
        int r = r0 + tid;
        float c = (r < rows) ? matv[r] : 0.f;
        float smin = fdekey(mm2[0]), smax = fdekey(mm2[1]);
        sh_c[tid] = c;
        sh_M[tid] = (c >= 0.f) ? c * smax : c * smin;
    }
    __syncthreads();
    float crow = sh_c[row], Mrow = sh_M[row];
    bool  rok  = (r0 + row) < rows;
    const float* arow = adj + (size_t)(rok ? (r0 + row) : 0) * N_NODE;
    float dpart = 0.f, zpart = 0.f;

    int wv = tid >> 6, lane = tid & 63;
    int am = lane & 15, aq = lane >> 4;
    f32x4 acc[8];
    #pragma unroll
    for (int n = 0; n < 8; n++) acc[n] = (f32x4){0.f,0.f,0.f,0.f};

    for (int t = 0; t < CS2 / 64; t++){
        int k0 = ch * CS2 + t * 64;
        __syncthreads();
        unsigned short h[16];
        #pragma unroll
        for (int u = 0; u < 16; u++){
            int j = k0 + j16 + u;
            float w = 0.f;
            if (j < N_NODE){
                float e = __expf(crow * s_v[j] - Mrow);
                zpart += e;
                if (rok) w = e * arow[j];
            }
            dpart += w;
            h[u] = f2bf(w);
        }
        uint4* dst = (uint4*)&sh_w[row * WPAD + j16];
        dst[0] = make_uint4(((unsigned)h[1]<<16)|h[0], ((unsigned)h[3]<<16)|h[2],
                            ((unsigned)h[5]<<16)|h[4], ((unsigned)h[7]<<16)|h[6]);
        dst[1] = make_uint4(((unsigned)h[9]<<16)|h[8], ((unsigned)h[11]<<16)|h[10],
                            ((unsigned)h[13]<<16)|h[12],((unsigned)h[15]<<16)|h[14]);
        __syncthreads();
        #pragma unroll
        for (int ks = 0; ks < 2; ks++){
            bf16x8 afrag = *(const bf16x8*)&sh_w[(wv*16 + am) * WPAD + ks*32 + aq*8];
            #pragma unroll
            for (int n = 0; n < 8; n++){
                bf16x8 bfrag = *(const bf16x8*)&Et[(size_t)(n*16 + am) * KVPAD + k0 + ks*32 + aq*8];
                acc[n] = __builtin_amdgcn_mfma_f32_16x16x32_bf16(afrag, bfrag, acc[n], 0, 0, 0);
            }
        }
    }
    dpart += __shfl_xor(dpart, 1, 64); dpart += __shfl_xor(dpart, 2, 64);
    zpart += __shfl_xor(zpart, 1, 64); zpart += __shfl_xor(zpart, 2, 64);
    if ((tid & 3) == 0 && rok){
        float* d2 = part + ((size_t)(baseR + r0 + row) * NCH + ch) * RSTRIDE;
        d2[128] = dpart; d2[129] = zpart;
    }
    #pragma unroll
    for (int n = 0; n < 8; n++){
        #pragma unroll
        for (int r = 0; r < 4; r++){
            int rl = wv*16 + aq*4 + r;
            int rr = r0 + rl;
            if (rr < rows){
                float* d2 = part + ((size_t)(baseR + rr) * NCH + ch) * RSTRIDE;
                d2[n*16 + am] = acc[n][r];
            }
        }
    }
}

// ---------------------------------------------------------------------------
// Batched phase-2: reduce big-gate partials over NCH chunks + 4-way inter
// gate from precomputed small-gate buffers. One 128-thr block per row.
struct RIJob {
    const float* e0; float* out; const float* gA; const float* gB;
    const float* W; const float* b; int baseR; int nrows; int row0;
};
struct RIJobs { RIJob j[3]; int njobs; };

__global__ __launch_bounds__(128) void k_reduce_inter(
    RIJobs jobs, const float* __restrict__ part)
{
    __shared__ float sh[4][EMB];
    __shared__ float shW[EMB];
    int b = blockIdx.x;
    int ji = 0;
    for (int q = 1; q < jobs.njobs; q++) if (b >= jobs.j[q].row0) ji = q;
    RIJob J = jobs.j[ji];
    int r = b - J.row0;
    int d = threadIdx.x;
    float num = 0.f, den = 0.f, Z = 0.f;
    for (int c = 0; c < NCH; c++){
        const float* p = part + ((size_t)(J.baseR + r) * NCH + c) * RSTRIDE;
        num += p[d]; den += p[128]; Z += p[129];
    }
    sh[1][d] = num / (den + 1e-8f * Z);
    sh[0][d] = J.e0[(size_t)r * EMB + d];
    sh[2][d] = J.gA[(size_t)r * EMB + d];
    sh[3][d] = J.gB[(size_t)r * EMB + d];
    shW[d] = J.W[d];
    __syncthreads();
    float dots[4];
    #pragma unroll
    for (int g = 0; g < 4; g++){
        float acc = 0.f;
        for (int k = 0; k < EMB; k++) acc += sh[g][k] * shW[k];
        dots[g] = acc;
    }
    float bb = J.b[0];
    float s0 = __expf(dots[0] + bb), s1 = __expf(dots[1] + bb);
    float s2 = __expf(dots[2] + bb), s3 = __expf(dots[3] + bb);
    float inv = 1.f / (s0 + s1 + s2 + s3);
    J.out[(size_t)r * EMB + d] =
        (s0*sh[0][d] + s1*sh[1][d] + s2*sh[2][d] + s3*sh[3][d]) * inv;
}

// ---------------------------------------------------------------------------
extern "C" void kernel_launch(void* const* d_in, const int* in_sizes, int n_in,
                              void* d_out, int out_size, void* d_ws, size_t ws_size,
                              hipStream_t stream)
{
    const int*   adj_idx  = (const int*)d_in[0];
    const float* adj_val  = (const float*)d_in[1];
    const float* a_pv   = (const float*)d_in[2];
    const float* a_vp   = (const float*)d_in[3];
    const float* a_pcb  = (const float*)d_in[4];
    const float* a_cbp  = (const float*)d_in[5];
    const float* a_cbv  = (const float*)d_in[6];
    const float* a_vcb  = (const float*)d_in[7];
    const float* a_pcm  = (const float*)d_in[8];
    const float* a_cmp  = (const float*)d_in[9];
    const float* a_cmv  = (const float*)d_in[10];
    const float* a_vcm  = (const float*)d_in[11];
    const float* a_cbcm = (const float*)d_in[12];
    const float* a_cmcb = (const float*)d_in[13];
    const float* in_item = (const float*)d_in[14];
    const float* in_pri  = (const float*)d_in[15];
    const float* in_cb   = (const float*)d_in[16];
    const float* in_cm   = (const float*)d_in[17];
    const float* m_vp  = (const float*)d_in[18];
    const float* m_vcb = (const float*)d_in[19];
    const float* m_vcm = (const float*)d_in[20];
    const float* m_pv  = (const float*)d_in[21];
    const float* m_pcb = (const float*)d_in[22];
    const float* m_pcm = (const float*)d_in[23];
    const float* m_cbp = (const float*)d_in[24];
    const float* m_cbv = (const float*)d_in[25];
    const float* m_cbcm= (const float*)d_in[26];
    const float* m_cmp = (const float*)d_in[27];
    const float* m_cmv = (const float*)d_in[28];
    const float* m_cmcb= (const float*)d_in[29];
    const float* Wi = (const float*)d_in[30]; const float* bi = (const float*)d_in[31];
    const float* Wp = (const float*)d_in[32]; const float* bp = (const float*)d_in[33];
    const float* Wcb= (const float*)d_in[34]; const float* bcb= (const float*)d_in[35];
    const float* Wcm= (const float*)d_in[36]; const float* bcm= (const float*)d_in[37];

    float* ws = (float*)d_ws;
    size_t off = 0;
    auto alloc = [&](size_t n){ float* p = ws + off; off += (n + 63) & ~(size_t)63; return p; };
    float* buf_item = alloc((size_t)N_NODE * EMB);
    float* buf_pri  = alloc((size_t)N_PRICE * EMB);
    float* buf_cb   = alloc((size_t)N_CB * EMB);
    float* buf_cm   = alloc((size_t)N_CM * EMB);
    float* s_all    = alloc(N_NODE + N_PRICE + N_CB + N_CM);
    unsigned* mm    = (unsigned*)alloc(64);
    float* g1 = alloc((size_t)N_NODE * EMB);
    float* g3 = alloc((size_t)N_NODE * EMB);
    float* part = g1;                       // 650*64*132 = 5.49M floats, alias g1
    unsigned short* et_v = (unsigned short*)g3;  // 13.6 MB, alias g3
    int*   counts = (int*)alloc(N_NODE + 64);
    int*   offs   = (int*)alloc(N_NODE + 64);
    int*   cursor = (int*)alloc(N_NODE + 64);
    int*   scol   = (int*)alloc(NNZE);
    float* sval   = alloc(NNZE);
    unsigned short* et_p  = (unsigned short*)alloc(EMB * 128 / 2);
    unsigned short* et_cb = (unsigned short*)alloc(EMB * 64 / 2);
    unsigned short* et_cm = (unsigned short*)alloc(EMB * 512 / 2);
    float* g_pcb  = alloc((size_t)N_PRICE * EMB);
    float* g_pcm  = alloc((size_t)N_PRICE * EMB);
    float* g_cbp  = alloc((size_t)N_CB * EMB);
    float* g_cbcm = alloc((size_t)N_CB * EMB);
    float* g_cmp  = alloc((size_t)N_CM * EMB);
    float* g_cmcb = alloc((size_t)N_CM * EMB);

    float* out_item = (float*)d_out;
    float* out_pri  = (float*)d_out + (size_t)N_NODE * EMB;

    const float* s_v  = s_all;
    const float* s_p  = s_all + N_NODE;
    const float* s_cb = s_all + N_NODE + N_PRICE;
    const float* s_cm = s_all + N_NODE + N_PRICE + N_CB;

    const int totr = N_NODE + N_PRICE + N_CB + N_CM;

    // ---- CSR build (once; adjacency is layer-invariant) ----
    hipMemsetAsync(counts, 0, N_NODE * sizeof(int), stream);
    k_hist<<<(NNZE + 255)/256, 256, 0, stream>>>(adj_idx, counts);
    k_scan<<<1, SCAN_T, 0, stream>>>(counts, offs, cursor);
    k_scatter<<<(NNZE + 255)/256, 256, 0, stream>>>(adj_idx, adj_idx + NNZE,
                                                    adj_val, cursor, scol, sval);

    for (int layer = 0; layer < 2; layer++){
        const float* cv  = layer ? buf_item : in_item;
        const float* cp  = layer ? buf_pri  : in_pri;
        const float* ccb = layer ? buf_cb   : in_cb;
        const float* ccm = layer ? buf_cm   : in_cm;
        float* ov = layer ? out_item : buf_item;
        float* op = layer ? out_pri  : buf_pri;

        k_rowsum<<<(totr + 3)/4, 256, 0, stream>>>(cv, cp, ccb, ccm, s_all, mm);
        k_minmax<<<(totr + 255)/256, 256, 0, stream>>>(s_all, mm);

        // bf16 transposed operands for p/cb/cm-source gates
        k_cast_et<<<dim3(1, EMB), 256, 0, stream>>>(cp,  et_p,  N_PRICE, 128);
        k_cast_et<<<dim3(1, EMB), 256, 0, stream>>>(ccb, et_cb, N_CB,    64);
        k_cast_et<<<dim3(2, EMB), 256, 0, stream>>>(ccm, et_cm, N_CM,    512);

        // batched small gates (MFMA)
        GateJobs gj{};
        int nb = 0, nj = 0;
        auto addjob = [&](const float* adj_, const float* matv_,
                          const unsigned short* Et_, const float* s_,
                          const unsigned* mm2_, float* out_,
                          int K_, int Kpad_, int nrows_){
            gj.j[nj] = GateJob{adj_, matv_, Et_, s_, mm2_, out_,
                               K_, Kpad_, nrows_, nb};
            nb += (nrows_ + 63) / 64; nj++;
        };
        addjob(a_pcb, m_pcb, et_cb, s_cb, mm+4, g_pcb, N_CB,    64, N_PRICE);
        addjob(a_pcm, m_pcm, et_cm, s_cm, mm+6, g_pcm, N_CM,   512, N_PRICE);
        if (layer == 0){
            addjob(a_cbp,  m_cbp,  et_p,  s_p,  mm+2, g_cbp,  N_PRICE, 128, N_CB);
            addjob(a_cbcm, m_cbcm, et_cm, s_cm, mm+6, g_cbcm, N_CM,   512, N_CB);
            addjob(a_cmp,  m_cmp,  et_p,  s_p,  mm+2, g_cmp,  N_PRICE, 128, N_CM);
            addjob(a_cmcb, m_cmcb, et_cb, s_cb, mm+4, g_cmcb, N_CB,    64, N_CM);
        }
        gj.njobs = nj;
        k_gate_batch<<<nb, 256, 0, stream>>>(gj);

        // fused item update (3 intra gates + inter gate)
        FParams fp{};
        fp.g[0] = FGate{a_vp,  m_vp,  et_p,  mm+2, N_PRICE, 128, 0};
        fp.g[1] = FGate{a_vcb, m_vcb, et_cb, mm+4, N_CB,    64,  100};
        fp.g[2] = FGate{a_vcm, m_vcm, et_cm, mm+6, N_CM,    512, 150};
        k_item_fused<<<(N_NODE + 63)/64, 256, 0, stream>>>(
            fp, cv, s_all + N_NODE, Wi, bi, ov);

        k_spmm_csr<<<(N_NODE*64 + 255)/256, 256, 0, stream>>>(offs, scol, sval, cv, ov);

        // item-side bf16 transposed operand (aliases g3, now dead)
        k_cast_et<<<dim3((KVPAD + 255)/256, EMB), 256, 0, stream>>>(cv, et_v, N_NODE, KVPAD);

        k_intra_tv_mfma<<<((N_PRICE + 63)/64) * NCH, 256, 0, stream>>>(
            a_pv, m_pv, et_v, s_v, mm + 0, part, 0, N_PRICE);
        if (layer == 0){
            k_intra_tv_mfma<<<((N_CB + 63)/64) * NCH, 256, 0, stream>>>(
                a_cbv, m_cbv, et_v, s_v, mm + 0, part, N_PRICE, N_CB);
            k_intra_tv_mfma<<<((N_CM + 63)/64) * NCH, 256, 0, stream>>>(
                a_cmv, m_cmv, et_v, s_v, mm + 0, part, N_PRICE + N_CB, N_CM);
        }

        // batched phase-2 reduce + inter
        RIJobs rj{};
        rj.j[0] = RIJob{cp, op, g_pcb, g_pcm, Wp, bp, 0, N_PRICE, 0};
        int nrows_tot = N_PRICE;
        int njr = 1;
        if (layer == 0){
            rj.j[1] = RIJob{ccb, buf_cb, g_cbp, g_cbcm, Wcb, bcb,
                            N_PRICE, N_CB, nrows_tot};
            nrows_tot += N_CB; njr++;
            rj.j[2] = RIJob{ccm, buf_cm, g_cmp, g_cmcb, Wcm, bcm,
                            N_PRICE + N_CB, N_CM, nrows_tot};
            nrows_tot += N_CM; njr++;
        }
        rj.njobs = njr;
        k_reduce_inter<<<nrows_tot, 128, 0, stream>>>(rj, part);
    }
    (void)in_sizes; (void)n_in; (void)out_size; (void)ws_size;
}